// Round 20
// baseline (852.832 us; speedup 1.0000x reference)
//
#include <hip/hip_runtime.h>

#define BATCH   16384
#define IN_DIM  1024
#define OUT_DIM 4096
#define K_TOP   409

typedef _Float16 half8  __attribute__((ext_vector_type(8)));
typedef _Float16 half4v __attribute__((ext_vector_type(4)));
typedef float    f32x4  __attribute__((ext_vector_type(4)));

// workspace: flag | xh 32MB | wh 8MB | thr 128KB | cnt 128KB | col 4MB | np 4MB
#define WS_XH_OFF   256
#define WS_WH_OFF   (WS_XH_OFF + (size_t)BATCH * IN_DIM * 2)
#define WS_THR_OFF  (WS_WH_OFF + (size_t)OUT_DIM * IN_DIM * 2)
#define WS_CNT_OFF  (WS_THR_OFF + (size_t)BATCH * 8)
#define WS_COL_OFF  (WS_CNT_OFF + (size_t)BATCH * 8)
#define WS_NP_OFF   (WS_COL_OFF + (size_t)BATCH * 64 * 4)
#define WS_NEEDED   (WS_WH_OFF + (size_t)OUT_DIM * IN_DIM * 2)
#define WS_NEED2    (WS_NP_OFF + (size_t)BATCH * 64 * 4)

// ---------------------------------------------------------------- kernel A
__global__ __launch_bounds__(256)
void k_hasneg(const float* __restrict__ x, int n, int* __restrict__ flag) {
    const int stride = gridDim.x * blockDim.x;
    bool neg = false;
    for (int i = blockIdx.x * blockDim.x + threadIdx.x; i < n; i += stride)
        neg |= (x[i] < 0.0f);
    unsigned long long b = __ballot(neg);
    if (b != 0ULL && (threadIdx.x & 63) == 0)
        atomicOr(flag, 1);
}

// ---------------------------------------------------------------- kernel A2
__global__ __launch_bounds__(256)
void k_cvt(const float* __restrict__ x, const float* __restrict__ w,
           _Float16* __restrict__ xh, _Float16* __restrict__ wh,
           const int* __restrict__ flag) {
    const bool bipolar = (*flag == 0);
    const int stride = gridDim.x * blockDim.x;
    const int nx4 = BATCH * IN_DIM / 4;
    const int nw4 = OUT_DIM * IN_DIM / 4;
    for (int i = blockIdx.x * blockDim.x + threadIdx.x; i < nx4; i += stride) {
        float4 v = ((const float4*)x)[i];
        if (bipolar) {
            v.x = (v.x - 0.5f) * 2.0f; v.y = (v.y - 0.5f) * 2.0f;
            v.z = (v.z - 0.5f) * 2.0f; v.w = (v.w - 0.5f) * 2.0f;
        }
        ((half4v*)xh)[i] = half4v{ (_Float16)v.x, (_Float16)v.y,
                                   (_Float16)v.z, (_Float16)v.w };
    }
    for (int i = blockIdx.x * blockDim.x + threadIdx.x; i < nw4; i += stride) {
        float4 u = ((const float4*)w)[i];
        ((half4v*)wh)[i] = half4v{ (_Float16)u.x, (_Float16)u.y,
                                   (_Float16)u.z, (_Float16)u.w };
    }
}

// ---------------------------------------------------------------- kernel B
// (r16-proven: global_load_lds w16, pre-swizzled source, 0 bank conflicts)
__global__ __launch_bounds__(256)
void k_gemm16(const _Float16* __restrict__ xh, const _Float16* __restrict__ wh,
              float* __restrict__ out) {
    __shared__ _Float16 Ah[128 * 64];
    __shared__ _Float16 Bh[128 * 64];
    const int tid = threadIdx.x;
    const int bm = blockIdx.x, bn = blockIdx.y;
    const int lane = tid & 63;
    const int wv = tid >> 6;
    const int wm = wv >> 1, wn = wv & 1;
    const int lr = lane & 15, lk = lane >> 4;

    const int srow = (lane >> 3);
    const int sslot = (lane & 7) ^ srow;
    f32x4 acc[4][4] = {};

    const _Float16* aS[4]; const _Float16* bS[4];
    _Float16* aD[4]; _Float16* bD[4];
    #pragma unroll
    for (int i = 0; i < 4; ++i) {
        const int rb = i * 32 + wv * 8;
        aS[i] = xh + (size_t)(bm * 128 + rb + srow) * IN_DIM + sslot * 8;
        bS[i] = wh + (size_t)(bn * 128 + rb + srow) * IN_DIM + sslot * 8;
        aD[i] = &Ah[rb * 64];
        bD[i] = &Bh[rb * 64];
    }

    #pragma unroll 1
    for (int kt = 0; kt < IN_DIM; kt += 64) {
        __syncthreads();
        #pragma unroll
        for (int i = 0; i < 4; ++i) {
            __builtin_amdgcn_global_load_lds((const __attribute__((address_space(1))) void*)(aS[i] + kt), (__attribute__((address_space(3))) void*)aD[i], 16, 0, 0);
            __builtin_amdgcn_global_load_lds((const __attribute__((address_space(1))) void*)(bS[i] + kt), (__attribute__((address_space(3))) void*)bD[i], 16, 0, 0);
        }
        __syncthreads();
        #pragma unroll
        for (int h = 0; h < 2; ++h) {
            half8 af[4], bf[4];
            #pragma unroll
            for (int i = 0; i < 4; ++i) {
                const int ra = wm * 64 + i * 16 + lr;
                const int sa = (h * 4 + lk) ^ (ra & 7);
                af[i] = *(const half8*)&Ah[ra * 64 + (sa << 3)];
                const int rb = wn * 64 + i * 16 + lr;
                const int sb = (h * 4 + lk) ^ (rb & 7);
                bf[i] = *(const half8*)&Bh[rb * 64 + (sb << 3)];
            }
            #pragma unroll
            for (int i = 0; i < 4; ++i)
                #pragma unroll
                for (int j = 0; j < 4; ++j)
                    acc[i][j] = __builtin_amdgcn_mfma_f32_16x16x32_f16(
                        af[i], bf[j], acc[i][j], 0, 0, 0);
        }
    }
    #pragma unroll
    for (int i = 0; i < 4; ++i)
        #pragma unroll
        for (int j = 0; j < 4; ++j)
            #pragma unroll
            for (int q = 0; q < 4; ++q) {
                const int row = bm * 128 + wm * 64 + i * 16 + lk * 4 + q;
                const int col = bn * 128 + wn * 64 + j * 16 + lr;
                out[(size_t)row * OUT_DIM + col] = acc[i][j][q];
            }
}

// ---------------------------------------------------------------- kernel B'
__global__ __launch_bounds__(256)
void k_gemm_fb(const float* __restrict__ x, const float* __restrict__ w,
               float* __restrict__ out, const int* __restrict__ flag) {
    __shared__ _Float16 Ah[128 * 64];
    __shared__ _Float16 Bh[128 * 64];
    const int tid = threadIdx.x;
    const int bm = blockIdx.x, bn = blockIdx.y;
    const bool bipolar = (*flag == 0);
    const int lane = tid & 63;
    const int wv = tid >> 6;
    const int wm = wv >> 1, wn = wv & 1;
    const int lr = lane & 15, lk = lane >> 4;
    const int sr = tid >> 1;
    const int sc = (tid & 1) * 32;
    const float* xr = x + (size_t)(bm * 128 + sr) * IN_DIM;
    const float* wrow = w + (size_t)(bn * 128 + sr) * IN_DIM;
    f32x4 acc[4][4] = {};
    #pragma unroll 1
    for (int kt = 0; kt < IN_DIM; kt += 64) {
        __syncthreads();
        #pragma unroll
        for (int i = 0; i < 8; ++i) {
            const int c = sc + i * 4;
            const int off = sr * 64 + ((((c >> 3) ^ (sr & 7))) << 3) + (c & 7);
            float4 v = *(const float4*)&xr[kt + c];
            if (bipolar) {
                v.x = (v.x - 0.5f) * 2.0f; v.y = (v.y - 0.5f) * 2.0f;
                v.z = (v.z - 0.5f) * 2.0f; v.w = (v.w - 0.5f) * 2.0f;
            }
            *(half4v*)&Ah[off] = half4v{ (_Float16)v.x, (_Float16)v.y,
                                         (_Float16)v.z, (_Float16)v.w };
            float4 u = *(const float4*)&wrow[kt + c];
            *(half4v*)&Bh[off] = half4v{ (_Float16)u.x, (_Float16)u.y,
                                         (_Float16)u.z, (_Float16)u.w };
        }
        __syncthreads();
        #pragma unroll
        for (int h = 0; h < 2; ++h) {
            half8 af[4], bf[4];
            #pragma unroll
            for (int i = 0; i < 4; ++i) {
                const int ra = wm * 64 + i * 16 + lr;
                const int sa = (h * 4 + lk) ^ (ra & 7);
                af[i] = *(const half8*)&Ah[ra * 64 + (sa << 3)];
                const int rb = wn * 64 + i * 16 + lr;
                const int sb = (h * 4 + lk) ^ (rb & 7);
                bf[i] = *(const half8*)&Bh[rb * 64 + (sb << 3)];
            }
            #pragma unroll
            for (int i = 0; i < 4; ++i)
                #pragma unroll
                for (int j = 0; j < 4; ++j)
                    acc[i][j] = __builtin_amdgcn_mfma_f32_16x16x32_f16(
                        af[i], bf[j], acc[i][j], 0, 0, 0);
        }
    }
    #pragma unroll
    for (int i = 0; i < 4; ++i)
        #pragma unroll
        for (int j = 0; j < 4; ++j)
            #pragma unroll
            for (int q = 0; q < 4; ++q) {
                const int row = bm * 128 + wm * 64 + i * 16 + lk * 4 + q;
                const int col = bn * 128 + wn * 64 + j * 16 + lr;
                out[(size_t)row * OUT_DIM + col] = acc[i][j][q];
            }
}

// ---------------------------------------------------------------- kernel C1
// per row: vmax, 256-bin histogram of positives, boundary bin, window
// [tlo,thi] = bin +- 8e-3, classify (hi count, window records), meta out.
__global__ __launch_bounds__(256)
void k_sel1(const float* __restrict__ po, float2* __restrict__ thr,
            int2* __restrict__ cnt, int* __restrict__ rcol) {
    __shared__ unsigned int bins[256];
    __shared__ float fred[4];
    __shared__ unsigned int wsum[4];
    __shared__ int s_b;
    __shared__ unsigned int s_hi, s_slot;
    const int row = blockIdx.x;
    const int tid = threadIdx.x;
    const int lane = tid & 63, wq = tid >> 6;
    const float4* p4 = (const float4*)(po + (size_t)row * OUT_DIM);

    float4 rv[4];
    float vmax = -1e30f;
    #pragma unroll
    for (int u = 0; u < 4; ++u) {
        rv[u] = p4[tid + 256 * u];
        vmax = fmaxf(vmax, fmaxf(fmaxf(rv[u].x, rv[u].y), fmaxf(rv[u].z, rv[u].w)));
    }
    #pragma unroll
    for (int off = 32; off > 0; off >>= 1)
        vmax = fmaxf(vmax, __shfl_xor(vmax, off));
    if (lane == 0) fred[wq] = vmax;
    bins[tid] = 0;
    if (tid == 0) { s_hi = 0; s_slot = 0; s_b = 0; }
    __syncthreads();
    vmax = fmaxf(fmaxf(fmaxf(fred[0], fred[1]), fmaxf(fred[2], fred[3])), 1e-6f);
    const float scale = 256.0f / vmax;
    const float invscale = vmax * (1.0f / 256.0f);

    #pragma unroll
    for (int u = 0; u < 4; ++u) {
        #pragma unroll
        for (int e = 0; e < 4; ++e) {
            float f = (e == 0) ? rv[u].x : (e == 1) ? rv[u].y
                    : (e == 2) ? rv[u].z : rv[u].w;
            if (f > 0.0f) {
                int b = (int)(f * scale);
                if (b > 255) b = 255;
                atomicAdd(&bins[b], 1u);
            }
        }
    }
    __syncthreads();

    // descending scan: thread t owns bin 255-t
    const unsigned int c = bins[255 - tid];
    unsigned int sc = c;
    #pragma unroll
    for (int off = 1; off < 64; off <<= 1) {
        unsigned int t2 = __shfl_up(sc, off);
        if (lane >= off) sc += t2;
    }
    if (lane == 63) wsum[wq] = sc;
    __syncthreads();
    for (int q = 0; q < wq; ++q) sc += wsum[q];
    if ((int)sc >= K_TOP && (int)(sc - c) < K_TOP) s_b = 255 - tid;
    __syncthreads();
    const float delta = 8e-3f;
    const float thi = (float)(s_b + 1) * invscale + delta;
    const float tlo = (float)s_b * invscale - delta;

    #pragma unroll
    for (int u = 0; u < 4; ++u) {
        #pragma unroll
        for (int e = 0; e < 4; ++e) {
            float f = (e == 0) ? rv[u].x : (e == 1) ? rv[u].y
                    : (e == 2) ? rv[u].z : rv[u].w;
            if (f > thi) atomicAdd(&s_hi, 1u);
            else if (f >= tlo) {
                unsigned int p = atomicAdd(&s_slot, 1u);
                if (p < 64) rcol[row * 64 + p] = (tid + 256 * u) * 4 + e;
            }
        }
    }
    __syncthreads();
    if (tid == 0) {
        int nb = (int)s_slot;
        int krem = K_TOP - (int)s_hi;
        if (krem > nb) krem = nb;
        if (krem < 0) krem = 0;
        thr[row] = make_float2(thi, tlo);
        cnt[row] = make_int2(nb, krem);
    }
}

// ---------------------------------------------------------------- kernel C2
// one borderline record per LANE: EXACT r13 reference chain (single acc,
// ascending k, __fmaf_rn; bipolar inline with identical __fadd/__fmul _rn).
// Massively parallel -> chain latency hidden by TLP.
__global__ __launch_bounds__(256)
void k_sel2(const float* __restrict__ x, const float* __restrict__ w,
            const int2* __restrict__ cnt, const int* __restrict__ rcol,
            float* __restrict__ rnp, const int* __restrict__ flag) {
    const int gid = blockIdx.x * 256 + threadIdx.x;
    const int row = gid >> 6, slot = gid & 63;
    int nb = cnt[row].x; if (nb > 64) nb = 64;
    if (slot >= nb) return;
    const int col = rcol[row * 64 + slot];
    const bool bipolar = (*flag == 0);
    const float4* xr4 = (const float4*)(x + (size_t)row * IN_DIM);
    const float4* wr4 = (const float4*)(w + (size_t)col * IN_DIM);
    float p = 0.0f;
    #pragma unroll 4
    for (int i = 0; i < IN_DIM / 4; ++i) {
        float4 xv = xr4[i];
        float4 wv = wr4[i];
        if (bipolar) {
            xv.x = __fmul_rn(__fadd_rn(xv.x, -0.5f), 2.0f);
            xv.y = __fmul_rn(__fadd_rn(xv.y, -0.5f), 2.0f);
            xv.z = __fmul_rn(__fadd_rn(xv.z, -0.5f), 2.0f);
            xv.w = __fmul_rn(__fadd_rn(xv.w, -0.5f), 2.0f);
        }
        p = __fmaf_rn(xv.x, wv.x, p);
        p = __fmaf_rn(xv.y, wv.y, p);
        p = __fmaf_rn(xv.z, wv.z, p);
        p = __fmaf_rn(xv.w, wv.w, p);
    }
    rnp[row * 64 + slot] = p;
}

// ---------------------------------------------------------------- kernel C3
// per row: rank records (tie-inclusive, order-invariant), encode, L2 norm.
__global__ __launch_bounds__(256)
void k_sel3(float* __restrict__ po, const float2* __restrict__ thr,
            const int2* __restrict__ cnt, const int* __restrict__ rcol,
            const float* __restrict__ rnp) {
    __shared__ int bcol[64];
    __shared__ float bnp[64];
    __shared__ unsigned char bsel[64];
    __shared__ float fred[4];
    const int row = blockIdx.x;
    const int tid = threadIdx.x;
    const int lane = tid & 63, wq = tid >> 6;
    const float2 th = thr[row];
    const int2 cn = cnt[row];
    const float thi = th.x, tlo = th.y;
    const int nb = cn.x, krem = cn.y;
    const int nbc = nb > 64 ? 64 : nb;
    const bool need = (nb != krem);

    if (tid < nbc) { bcol[tid] = rcol[row * 64 + tid]; bnp[tid] = rnp[row * 64 + tid]; }
    __syncthreads();
    if (tid < nbc) {
        const float v = bnp[tid];
        int gc = 0;
        for (int l = 0; l < nbc; ++l) gc += (bnp[l] > v);
        bsel[tid] = (gc < krem) ? 1 : 0;
    }
    __syncthreads();

    float4* p4 = (float4*)(po + (size_t)row * OUT_DIM);
    float4 rv[4];
    float nrm2 = 0.0f;
    #pragma unroll
    for (int u = 0; u < 4; ++u) {
        float4 v = p4[tid + 256 * u];
        float4 o;
        #pragma unroll
        for (int e = 0; e < 4; ++e) {
            float f = (e == 0) ? v.x : (e == 1) ? v.y : (e == 2) ? v.z : v.w;
            bool sel = (f > thi);
            float val = f;
            if (!sel && f >= tlo) {
                if (!need) sel = true;
                else {
                    const int j = (tid + 256 * u) * 4 + e;
                    for (int m = 0; m < nbc; ++m)
                        if (bcol[m] == j) {
                            sel = (bsel[m] != 0);
                            val = bnp[m];
                            break;
                        }
                }
            }
            float eo = (sel && val > 0.0f) ? val : 0.0f;
            if (e == 0) o.x = eo; else if (e == 1) o.y = eo;
            else if (e == 2) o.z = eo; else o.w = eo;
            nrm2 += eo * eo;
        }
        rv[u] = o;
    }
    #pragma unroll
    for (int off = 32; off > 0; off >>= 1)
        nrm2 += __shfl_xor(nrm2, off);
    if (lane == 0) fred[wq] = nrm2;
    __syncthreads();
    const float total = fred[0] + fred[1] + fred[2] + fred[3];
    const float inv = 1.0f / fmaxf(sqrtf(total), 1e-12f);
    #pragma unroll
    for (int u = 0; u < 4; ++u) {
        float4 e = rv[u];
        e.x *= inv; e.y *= inv; e.z *= inv; e.w *= inv;
        p4[tid + 256 * u] = e;
    }
}

// ---------------------------------------------------------------- kernel C (fallback, r19-proven monolithic)
__global__ __launch_bounds__(256)
void k_select_mono(float* __restrict__ po, const float* __restrict__ x,
                   const float* __restrict__ w, const int* __restrict__ flag) {
    __shared__ unsigned int bins[4][256];
    __shared__ float xs[4][IN_DIM];
    __shared__ int bl_idx[4][64];
    __shared__ float bl_np[4][64];
    __shared__ unsigned char bl_sel[4][64];
    __shared__ int s_bstar[4];
    __shared__ unsigned int s_slot[4];

    const int tid = threadIdx.x;
    const int lane = tid & 63;
    const int wv = tid >> 6;
    const int row = blockIdx.x * 4 + wv;
    float* prow = po + (size_t)row * OUT_DIM;
    const float4* prow4 = (const float4*)prow;

    float4 r[16];
    float vmax = -1e30f;
    #pragma unroll
    for (int u = 0; u < 16; ++u) {
        r[u] = prow4[lane + 64 * u];
        vmax = fmaxf(vmax, fmaxf(fmaxf(r[u].x, r[u].y), fmaxf(r[u].z, r[u].w)));
    }
    #pragma unroll
    for (int off = 32; off > 0; off >>= 1)
        vmax = fmaxf(vmax, __shfl_xor(vmax, off));
    vmax = fmaxf(vmax, 1e-6f);
    const float scale = 256.0f / vmax;
    const float invscale = vmax * (1.0f / 256.0f);

    #pragma unroll
    for (int u = 0; u < 4; ++u) bins[wv][lane + 64 * u] = 0;
    if (lane == 0) { s_bstar[wv] = 0; s_slot[wv] = 0; }
    __syncthreads();
    #pragma unroll
    for (int u = 0; u < 16; ++u) {
        #pragma unroll
        for (int e = 0; e < 4; ++e) {
            float f = (e == 0) ? r[u].x : (e == 1) ? r[u].y
                    : (e == 2) ? r[u].z : r[u].w;
            if (f > 0.0f) {
                int b = (int)(f * scale);
                if (b > 255) b = 255;
                atomicAdd(&bins[wv][b], 1u);
            }
        }
    }
    __syncthreads();
    const int g = 63 - lane;
    const unsigned int c = bins[wv][4 * g] + bins[wv][4 * g + 1]
                         + bins[wv][4 * g + 2] + bins[wv][4 * g + 3];
    unsigned int sc = c;
    #pragma unroll
    for (int off = 1; off < 64; off <<= 1) {
        unsigned int t2 = __shfl_up(sc, off);
        if (lane >= off) sc += t2;
    }
    if ((int)sc >= K_TOP && (int)(sc - c) < K_TOP) {
        int cum = (int)(sc - c);
        int bstar = 4 * g;
        for (int bi = 4 * g + 3; bi >= 4 * g; --bi) {
            cum += (int)bins[wv][bi];
            if (cum >= K_TOP) { bstar = bi; break; }
        }
        s_bstar[wv] = bstar;
    }
    __syncthreads();
    const int bstar = s_bstar[wv];
    const float delta = 8e-3f;
    const float thi = (float)(bstar + 1) * invscale + delta;
    const float tlo = (float)bstar * invscale - delta;

    int hi = 0, nb = 0;
    #pragma unroll
    for (int u = 0; u < 16; ++u) {
        #pragma unroll
        for (int e = 0; e < 4; ++e) {
            float f = (e == 0) ? r[u].x : (e == 1) ? r[u].y
                    : (e == 2) ? r[u].z : r[u].w;
            bool isbl = (f <= thi) && (f >= tlo);
            hi += (int)__popcll(__ballot(f > thi));
            nb += (int)__popcll(__ballot(isbl));
            if (isbl) {
                unsigned int p = atomicAdd(&s_slot[wv], 1u);
                if (p < 64) bl_idx[wv][p] = (lane + 64 * u) * 4 + e;
            }
        }
    }
    int nbc = nb > 64 ? 64 : nb;
    int krem = K_TOP - hi; if (krem > nb) krem = nb; if (krem < 0) krem = 0;
    const bool need = (nb != krem);

    const int anyneed = __syncthreads_or(need ? 1 : 0);
    if (anyneed) {
        if (need) {
            const bool bipolar = (*flag == 0);
            const float4* xr4 = (const float4*)(x + (size_t)row * IN_DIM);
            #pragma unroll
            for (int u = 0; u < 4; ++u) {
                float4 xv = xr4[lane + 64 * u];
                if (bipolar) {
                    xv.x = __fmul_rn(__fadd_rn(xv.x, -0.5f), 2.0f);
                    xv.y = __fmul_rn(__fadd_rn(xv.y, -0.5f), 2.0f);
                    xv.z = __fmul_rn(__fadd_rn(xv.z, -0.5f), 2.0f);
                    xv.w = __fmul_rn(__fadd_rn(xv.w, -0.5f), 2.0f);
                }
                ((float4*)xs[wv])[lane + 64 * u] = xv;
            }
        }
        __syncthreads();
        if (need && lane < nbc) {
            const float4* wr4 = (const float4*)(w + (size_t)bl_idx[wv][lane] * IN_DIM);
            const float4* xs4 = (const float4*)xs[wv];
            float p = 0.0f;
            #pragma unroll 4
            for (int i = 0; i < IN_DIM / 4; ++i) {
                float4 xv = xs4[i];
                float4 wvv = wr4[i];
                p = __fmaf_rn(xv.x, wvv.x, p);
                p = __fmaf_rn(xv.y, wvv.y, p);
                p = __fmaf_rn(xv.z, wvv.z, p);
                p = __fmaf_rn(xv.w, wvv.w, p);
            }
            bl_np[wv][lane] = p;
        }
        __syncthreads();
        if (need && lane < nbc) {
            const float v = bl_np[wv][lane];
            int gcount = 0;
            for (int l = 0; l < nbc; ++l) gcount += (bl_np[wv][l] > v);
            bl_sel[wv][lane] = (gcount < krem) ? 1 : 0;
        }
        __syncthreads();
    }

    float nrm2 = 0.0f;
    #pragma unroll
    for (int u = 0; u < 16; ++u) {
        float4 o;
        #pragma unroll
        for (int e = 0; e < 4; ++e) {
            float f = (e == 0) ? r[u].x : (e == 1) ? r[u].y
                    : (e == 2) ? r[u].z : r[u].w;
            bool sel = (f > thi);
            float val = f;
            if (!sel && f >= tlo) {
                if (!need) sel = true;
                else {
                    const int j = (lane + 64 * u) * 4 + e;
                    sel = false;
                    for (int m = 0; m < nbc; ++m)
                        if (bl_idx[wv][m] == j) {
                            sel = (bl_sel[wv][m] != 0);
                            val = bl_np[wv][m];
                            break;
                        }
                }
            }
            float eo = (sel && val > 0.0f) ? val : 0.0f;
            if (e == 0) o.x = eo; else if (e == 1) o.y = eo;
            else if (e == 2) o.z = eo; else o.w = eo;
            nrm2 += eo * eo;
        }
        r[u] = o;
    }
    #pragma unroll
    for (int off = 32; off > 0; off >>= 1)
        nrm2 += __shfl_xor(nrm2, off);
    const float inv = 1.0f / fmaxf(sqrtf(nrm2), 1e-12f);
    #pragma unroll
    for (int u = 0; u < 16; ++u) {
        float4 e = r[u];
        e.x *= inv; e.y *= inv; e.z *= inv; e.w *= inv;
        ((float4*)prow)[lane + 64 * u] = e;
    }
}

// ---------------------------------------------------------------- launch
extern "C" void kernel_launch(void* const* d_in, const int* in_sizes, int n_in,
                              void* d_out, int out_size, void* d_ws, size_t ws_size,
                              hipStream_t stream) {
    const float* x = (const float*)d_in[0];
    const float* w = (const float*)d_in[1];
    float* out = (float*)d_out;
    int* flag = (int*)d_ws;

    hipMemsetAsync(flag, 0, sizeof(int), stream);
    k_hasneg<<<2048, 256, 0, stream>>>(x, BATCH * IN_DIM, flag);

    dim3 g(BATCH / 128, OUT_DIM / 128);
    if (ws_size >= WS_NEEDED) {
        _Float16* xh = (_Float16*)((char*)d_ws + WS_XH_OFF);
        _Float16* wh = (_Float16*)((char*)d_ws + WS_WH_OFF);
        k_cvt<<<2048, 256, 0, stream>>>(x, w, xh, wh, flag);
        k_gemm16<<<g, 256, 0, stream>>>(xh, wh, out);
    } else {
        k_gemm_fb<<<g, 256, 0, stream>>>(x, w, out, flag);
    }

    if (ws_size >= WS_NEED2) {
        float2* thr = (float2*)((char*)d_ws + WS_THR_OFF);
        int2*   cnt = (int2*)((char*)d_ws + WS_CNT_OFF);
        int*    rcol = (int*)((char*)d_ws + WS_COL_OFF);
        float*  rnp = (float*)((char*)d_ws + WS_NP_OFF);
        k_sel1<<<BATCH, 256, 0, stream>>>(out, thr, cnt, rcol);
        k_sel2<<<BATCH * 64 / 256, 256, 0, stream>>>(x, w, cnt, rcol, rnp, flag);
        k_sel3<<<BATCH, 256, 0, stream>>>(out, thr, cnt, rcol, rnp);
    } else {
        k_select_mono<<<BATCH / 4, 256, 0, stream>>>(out, x, w, flag);
    }
}

// Round 21
// 732.332 us; speedup vs baseline: 1.1645x; 1.1645x over previous
//
#include <hip/hip_runtime.h>

#define BATCH   16384
#define IN_DIM  1024
#define OUT_DIM 4096
#define K_TOP   409

typedef _Float16 half8  __attribute__((ext_vector_type(8)));
typedef _Float16 half4v __attribute__((ext_vector_type(4)));
typedef float    f32x4  __attribute__((ext_vector_type(4)));

// workspace: flag | xh 32MB | wh 8MB | thr 128KB | cnt 128KB | col 4MB | np 4MB
#define WS_XH_OFF   256
#define WS_WH_OFF   (WS_XH_OFF + (size_t)BATCH * IN_DIM * 2)
#define WS_THR_OFF  (WS_WH_OFF + (size_t)OUT_DIM * IN_DIM * 2)
#define WS_CNT_OFF  (WS_THR_OFF + (size_t)BATCH * 8)
#define WS_COL_OFF  (WS_CNT_OFF + (size_t)BATCH * 8)
#define WS_NP_OFF   (WS_COL_OFF + (size_t)BATCH * 64 * 4)
#define WS_NEEDED   (WS_WH_OFF + (size_t)OUT_DIM * IN_DIM * 2)
#define WS_NEED2    (WS_NP_OFF + (size_t)BATCH * 64 * 4)

// ---------------------------------------------------------------- kernel A
__global__ __launch_bounds__(256)
void k_hasneg(const float* __restrict__ x, int n, int* __restrict__ flag) {
    const int stride = gridDim.x * blockDim.x;
    bool neg = false;
    for (int i = blockIdx.x * blockDim.x + threadIdx.x; i < n; i += stride)
        neg |= (x[i] < 0.0f);
    unsigned long long b = __ballot(neg);
    if (b != 0ULL && (threadIdx.x & 63) == 0)
        atomicOr(flag, 1);
}

// ---------------------------------------------------------------- kernel A2
__global__ __launch_bounds__(256)
void k_cvt(const float* __restrict__ x, const float* __restrict__ w,
           _Float16* __restrict__ xh, _Float16* __restrict__ wh,
           const int* __restrict__ flag) {
    const bool bipolar = (*flag == 0);
    const int stride = gridDim.x * blockDim.x;
    const int nx4 = BATCH * IN_DIM / 4;
    const int nw4 = OUT_DIM * IN_DIM / 4;
    for (int i = blockIdx.x * blockDim.x + threadIdx.x; i < nx4; i += stride) {
        float4 v = ((const float4*)x)[i];
        if (bipolar) {
            v.x = (v.x - 0.5f) * 2.0f; v.y = (v.y - 0.5f) * 2.0f;
            v.z = (v.z - 0.5f) * 2.0f; v.w = (v.w - 0.5f) * 2.0f;
        }
        ((half4v*)xh)[i] = half4v{ (_Float16)v.x, (_Float16)v.y,
                                   (_Float16)v.z, (_Float16)v.w };
    }
    for (int i = blockIdx.x * blockDim.x + threadIdx.x; i < nw4; i += stride) {
        float4 u = ((const float4*)w)[i];
        ((half4v*)wh)[i] = half4v{ (_Float16)u.x, (_Float16)u.y,
                                   (_Float16)u.z, (_Float16)u.w };
    }
}

// ---------------------------------------------------------------- kernel B
// (r16-proven: global_load_lds w16, pre-swizzled source, 0 bank conflicts)
__global__ __launch_bounds__(256)
void k_gemm16(const _Float16* __restrict__ xh, const _Float16* __restrict__ wh,
              float* __restrict__ out) {
    __shared__ _Float16 Ah[128 * 64];
    __shared__ _Float16 Bh[128 * 64];
    const int tid = threadIdx.x;
    const int bm = blockIdx.x, bn = blockIdx.y;
    const int lane = tid & 63;
    const int wv = tid >> 6;
    const int wm = wv >> 1, wn = wv & 1;
    const int lr = lane & 15, lk = lane >> 4;

    const int srow = (lane >> 3);
    const int sslot = (lane & 7) ^ srow;
    f32x4 acc[4][4] = {};

    const _Float16* aS[4]; const _Float16* bS[4];
    _Float16* aD[4]; _Float16* bD[4];
    #pragma unroll
    for (int i = 0; i < 4; ++i) {
        const int rb = i * 32 + wv * 8;
        aS[i] = xh + (size_t)(bm * 128 + rb + srow) * IN_DIM + sslot * 8;
        bS[i] = wh + (size_t)(bn * 128 + rb + srow) * IN_DIM + sslot * 8;
        aD[i] = &Ah[rb * 64];
        bD[i] = &Bh[rb * 64];
    }

    #pragma unroll 1
    for (int kt = 0; kt < IN_DIM; kt += 64) {
        __syncthreads();
        #pragma unroll
        for (int i = 0; i < 4; ++i) {
            __builtin_amdgcn_global_load_lds((const __attribute__((address_space(1))) void*)(aS[i] + kt), (__attribute__((address_space(3))) void*)aD[i], 16, 0, 0);
            __builtin_amdgcn_global_load_lds((const __attribute__((address_space(1))) void*)(bS[i] + kt), (__attribute__((address_space(3))) void*)bD[i], 16, 0, 0);
        }
        __syncthreads();
        #pragma unroll
        for (int h = 0; h < 2; ++h) {
            half8 af[4], bf[4];
            #pragma unroll
            for (int i = 0; i < 4; ++i) {
                const int ra = wm * 64 + i * 16 + lr;
                const int sa = (h * 4 + lk) ^ (ra & 7);
                af[i] = *(const half8*)&Ah[ra * 64 + (sa << 3)];
                const int rb = wn * 64 + i * 16 + lr;
                const int sb = (h * 4 + lk) ^ (rb & 7);
                bf[i] = *(const half8*)&Bh[rb * 64 + (sb << 3)];
            }
            #pragma unroll
            for (int i = 0; i < 4; ++i)
                #pragma unroll
                for (int j = 0; j < 4; ++j)
                    acc[i][j] = __builtin_amdgcn_mfma_f32_16x16x32_f16(
                        af[i], bf[j], acc[i][j], 0, 0, 0);
        }
    }
    #pragma unroll
    for (int i = 0; i < 4; ++i)
        #pragma unroll
        for (int j = 0; j < 4; ++j)
            #pragma unroll
            for (int q = 0; q < 4; ++q) {
                const int row = bm * 128 + wm * 64 + i * 16 + lk * 4 + q;
                const int col = bn * 128 + wn * 64 + j * 16 + lr;
                out[(size_t)row * OUT_DIM + col] = acc[i][j][q];
            }
}

// ---------------------------------------------------------------- kernel B'
__global__ __launch_bounds__(256)
void k_gemm_fb(const float* __restrict__ x, const float* __restrict__ w,
               float* __restrict__ out, const int* __restrict__ flag) {
    __shared__ _Float16 Ah[128 * 64];
    __shared__ _Float16 Bh[128 * 64];
    const int tid = threadIdx.x;
    const int bm = blockIdx.x, bn = blockIdx.y;
    const bool bipolar = (*flag == 0);
    const int lane = tid & 63;
    const int wv = tid >> 6;
    const int wm = wv >> 1, wn = wv & 1;
    const int lr = lane & 15, lk = lane >> 4;
    const int sr = tid >> 1;
    const int sc = (tid & 1) * 32;
    const float* xr = x + (size_t)(bm * 128 + sr) * IN_DIM;
    const float* wrow = w + (size_t)(bn * 128 + sr) * IN_DIM;
    f32x4 acc[4][4] = {};
    #pragma unroll 1
    for (int kt = 0; kt < IN_DIM; kt += 64) {
        __syncthreads();
        #pragma unroll
        for (int i = 0; i < 8; ++i) {
            const int c = sc + i * 4;
            const int off = sr * 64 + ((((c >> 3) ^ (sr & 7))) << 3) + (c & 7);
            float4 v = *(const float4*)&xr[kt + c];
            if (bipolar) {
                v.x = (v.x - 0.5f) * 2.0f; v.y = (v.y - 0.5f) * 2.0f;
                v.z = (v.z - 0.5f) * 2.0f; v.w = (v.w - 0.5f) * 2.0f;
            }
            *(half4v*)&Ah[off] = half4v{ (_Float16)v.x, (_Float16)v.y,
                                         (_Float16)v.z, (_Float16)v.w };
            float4 u = *(const float4*)&wrow[kt + c];
            *(half4v*)&Bh[off] = half4v{ (_Float16)u.x, (_Float16)u.y,
                                         (_Float16)u.z, (_Float16)u.w };
        }
        __syncthreads();
        #pragma unroll
        for (int h = 0; h < 2; ++h) {
            half8 af[4], bf[4];
            #pragma unroll
            for (int i = 0; i < 4; ++i) {
                const int ra = wm * 64 + i * 16 + lr;
                const int sa = (h * 4 + lk) ^ (ra & 7);
                af[i] = *(const half8*)&Ah[ra * 64 + (sa << 3)];
                const int rb = wn * 64 + i * 16 + lr;
                const int sb = (h * 4 + lk) ^ (rb & 7);
                bf[i] = *(const half8*)&Bh[rb * 64 + (sb << 3)];
            }
            #pragma unroll
            for (int i = 0; i < 4; ++i)
                #pragma unroll
                for (int j = 0; j < 4; ++j)
                    acc[i][j] = __builtin_amdgcn_mfma_f32_16x16x32_f16(
                        af[i], bf[j], acc[i][j], 0, 0, 0);
        }
    }
    #pragma unroll
    for (int i = 0; i < 4; ++i)
        #pragma unroll
        for (int j = 0; j < 4; ++j)
            #pragma unroll
            for (int q = 0; q < 4; ++q) {
                const int row = bm * 128 + wm * 64 + i * 16 + lk * 4 + q;
                const int col = bn * 128 + wn * 64 + j * 16 + lr;
                out[(size_t)row * OUT_DIM + col] = acc[i][j][q];
            }
}

// ---------------------------------------------------------------- kernel C1
__global__ __launch_bounds__(256)
void k_sel1(const float* __restrict__ po, float2* __restrict__ thr,
            int2* __restrict__ cnt, int* __restrict__ rcol) {
    __shared__ unsigned int bins[256];
    __shared__ float fred[4];
    __shared__ unsigned int wsum[4];
    __shared__ int s_b;
    __shared__ unsigned int s_hi, s_slot;
    const int row = blockIdx.x;
    const int tid = threadIdx.x;
    const int lane = tid & 63, wq = tid >> 6;
    const float4* p4 = (const float4*)(po + (size_t)row * OUT_DIM);

    float4 rv[4];
    float vmax = -1e30f;
    #pragma unroll
    for (int u = 0; u < 4; ++u) {
        rv[u] = p4[tid + 256 * u];
        vmax = fmaxf(vmax, fmaxf(fmaxf(rv[u].x, rv[u].y), fmaxf(rv[u].z, rv[u].w)));
    }
    #pragma unroll
    for (int off = 32; off > 0; off >>= 1)
        vmax = fmaxf(vmax, __shfl_xor(vmax, off));
    if (lane == 0) fred[wq] = vmax;
    bins[tid] = 0;
    if (tid == 0) { s_hi = 0; s_slot = 0; s_b = 0; }
    __syncthreads();
    vmax = fmaxf(fmaxf(fmaxf(fred[0], fred[1]), fmaxf(fred[2], fred[3])), 1e-6f);
    const float scale = 256.0f / vmax;
    const float invscale = vmax * (1.0f / 256.0f);

    #pragma unroll
    for (int u = 0; u < 4; ++u) {
        #pragma unroll
        for (int e = 0; e < 4; ++e) {
            float f = (e == 0) ? rv[u].x : (e == 1) ? rv[u].y
                    : (e == 2) ? rv[u].z : rv[u].w;
            if (f > 0.0f) {
                int b = (int)(f * scale);
                if (b > 255) b = 255;
                atomicAdd(&bins[b], 1u);
            }
        }
    }
    __syncthreads();

    const unsigned int c = bins[255 - tid];
    unsigned int sc = c;
    #pragma unroll
    for (int off = 1; off < 64; off <<= 1) {
        unsigned int t2 = __shfl_up(sc, off);
        if (lane >= off) sc += t2;
    }
    if (lane == 63) wsum[wq] = sc;
    __syncthreads();
    for (int q = 0; q < wq; ++q) sc += wsum[q];
    if ((int)sc >= K_TOP && (int)(sc - c) < K_TOP) s_b = 255 - tid;
    __syncthreads();
    const float delta = 8e-3f;
    const float thi = (float)(s_b + 1) * invscale + delta;
    const float tlo = (float)s_b * invscale - delta;

    #pragma unroll
    for (int u = 0; u < 4; ++u) {
        #pragma unroll
        for (int e = 0; e < 4; ++e) {
            float f = (e == 0) ? rv[u].x : (e == 1) ? rv[u].y
                    : (e == 2) ? rv[u].z : rv[u].w;
            if (f > thi) atomicAdd(&s_hi, 1u);
            else if (f >= tlo) {
                unsigned int p = atomicAdd(&s_slot, 1u);
                if (p < 64) rcol[row * 64 + p] = (tid + 256 * u) * 4 + e;
            }
        }
    }
    __syncthreads();
    if (tid == 0) {
        int nb = (int)s_slot;
        int krem = K_TOP - (int)s_hi;
        if (krem > nb) krem = nb;
        if (krem < 0) krem = 0;
        thr[row] = make_float2(thi, tlo);
        cnt[row] = make_int2(nb, krem);
    }
}

// ---------------------------------------------------------------- kernel C2
// 4 rows/block, ONE WAVE PER ROW, one record per LANE. The wave stages the
// bipolar-converted x row into LDS ONCE (uniform control flow, one barrier),
// then each lane's chain reads x via ds_read_b128 (no per-record bipolar /
// x reload -- r20 showed those were ~5x the FMA issue) and prefetches w with
// the r17-proven 2-stage register double-buffer. Chain arithmetic is the
// EXACT r13 reference sequence: single acc, ascending k, __fmaf_rn.
__global__ __launch_bounds__(256)
void k_sel2(const float* __restrict__ x, const float* __restrict__ w,
            const int2* __restrict__ cnt, const int* __restrict__ rcol,
            float* __restrict__ rnp, const int* __restrict__ flag) {
    __shared__ float xs[4][IN_DIM];          // 16 KB
    const int tid = threadIdx.x;
    const int lane = tid & 63;
    const int wv = tid >> 6;
    const int row = blockIdx.x * 4 + wv;
    const bool bipolar = (*flag == 0);

    // stage bipolar x row (identical __fadd_rn/__fmul_rn ops as reference)
    const float4* xr4 = (const float4*)(x + (size_t)row * IN_DIM);
    #pragma unroll
    for (int u = 0; u < 4; ++u) {
        float4 xv = xr4[lane + 64 * u];
        if (bipolar) {
            xv.x = __fmul_rn(__fadd_rn(xv.x, -0.5f), 2.0f);
            xv.y = __fmul_rn(__fadd_rn(xv.y, -0.5f), 2.0f);
            xv.z = __fmul_rn(__fadd_rn(xv.z, -0.5f), 2.0f);
            xv.w = __fmul_rn(__fadd_rn(xv.w, -0.5f), 2.0f);
        }
        ((float4*)xs[wv])[lane + 64 * u] = xv;
    }
    __syncthreads();

    int nb = cnt[row].x; if (nb > 64) nb = 64;
    if (lane < nb) {
        const int col = rcol[row * 64 + lane];
        const float4* wr4 = (const float4*)(w + (size_t)col * IN_DIM);
        const float4* xs4 = (const float4*)xs[wv];
        float4 bA[8], bB[8];
        #pragma unroll
        for (int u = 0; u < 8; ++u) bA[u] = wr4[u];
        float p = 0.0f;
        #pragma unroll 1
        for (int gg = 0; gg < 16; ++gg) {
            #pragma unroll
            for (int u = 0; u < 8; ++u) bB[u] = wr4[(2 * gg + 1) * 8 + u];
            #pragma unroll
            for (int u = 0; u < 8; ++u) {
                float4 xv = xs4[(2 * gg) * 8 + u];
                p = __fmaf_rn(xv.x, bA[u].x, p);
                p = __fmaf_rn(xv.y, bA[u].y, p);
                p = __fmaf_rn(xv.z, bA[u].z, p);
                p = __fmaf_rn(xv.w, bA[u].w, p);
            }
            if (gg < 15) {
                #pragma unroll
                for (int u = 0; u < 8; ++u) bA[u] = wr4[(2 * gg + 2) * 8 + u];
            }
            #pragma unroll
            for (int u = 0; u < 8; ++u) {
                float4 xv = xs4[(2 * gg + 1) * 8 + u];
                p = __fmaf_rn(xv.x, bB[u].x, p);
                p = __fmaf_rn(xv.y, bB[u].y, p);
                p = __fmaf_rn(xv.z, bB[u].z, p);
                p = __fmaf_rn(xv.w, bB[u].w, p);
            }
        }
        rnp[row * 64 + lane] = p;
    }
}

// ---------------------------------------------------------------- kernel C3
__global__ __launch_bounds__(256)
void k_sel3(float* __restrict__ po, const float2* __restrict__ thr,
            const int2* __restrict__ cnt, const int* __restrict__ rcol,
            const float* __restrict__ rnp) {
    __shared__ int bcol[64];
    __shared__ float bnp[64];
    __shared__ unsigned char bsel[64];
    __shared__ float fred[4];
    const int row = blockIdx.x;
    const int tid = threadIdx.x;
    const int lane = tid & 63, wq = tid >> 6;
    const float2 th = thr[row];
    const int2 cn = cnt[row];
    const float thi = th.x, tlo = th.y;
    const int nb = cn.x, krem = cn.y;
    const int nbc = nb > 64 ? 64 : nb;
    const bool need = (nb != krem);

    if (tid < nbc) { bcol[tid] = rcol[row * 64 + tid]; bnp[tid] = rnp[row * 64 + tid]; }
    __syncthreads();
    if (tid < nbc) {
        const float v = bnp[tid];
        int gc = 0;
        for (int l = 0; l < nbc; ++l) gc += (bnp[l] > v);
        bsel[tid] = (gc < krem) ? 1 : 0;
    }
    __syncthreads();

    float4* p4 = (float4*)(po + (size_t)row * OUT_DIM);
    float4 rv[4];
    float nrm2 = 0.0f;
    #pragma unroll
    for (int u = 0; u < 4; ++u) {
        float4 v = p4[tid + 256 * u];
        float4 o;
        #pragma unroll
        for (int e = 0; e < 4; ++e) {
            float f = (e == 0) ? v.x : (e == 1) ? v.y : (e == 2) ? v.z : v.w;
            bool sel = (f > thi);
            float val = f;
            if (!sel && f >= tlo) {
                if (!need) sel = true;
                else {
                    const int j = (tid + 256 * u) * 4 + e;
                    for (int m = 0; m < nbc; ++m)
                        if (bcol[m] == j) {
                            sel = (bsel[m] != 0);
                            val = bnp[m];
                            break;
                        }
                }
            }
            float eo = (sel && val > 0.0f) ? val : 0.0f;
            if (e == 0) o.x = eo; else if (e == 1) o.y = eo;
            else if (e == 2) o.z = eo; else o.w = eo;
            nrm2 += eo * eo;
        }
        rv[u] = o;
    }
    #pragma unroll
    for (int off = 32; off > 0; off >>= 1)
        nrm2 += __shfl_xor(nrm2, off);
    if (lane == 0) fred[wq] = nrm2;
    __syncthreads();
    const float total = fred[0] + fred[1] + fred[2] + fred[3];
    const float inv = 1.0f / fmaxf(sqrtf(total), 1e-12f);
    #pragma unroll
    for (int u = 0; u < 4; ++u) {
        float4 e = rv[u];
        e.x *= inv; e.y *= inv; e.z *= inv; e.w *= inv;
        p4[tid + 256 * u] = e;
    }
}

// ---------------------------------------------------------------- kernel C (fallback, r19-proven monolithic)
__global__ __launch_bounds__(256)
void k_select_mono(float* __restrict__ po, const float* __restrict__ x,
                   const float* __restrict__ w, const int* __restrict__ flag) {
    __shared__ unsigned int bins[4][256];
    __shared__ float xs[4][IN_DIM];
    __shared__ int bl_idx[4][64];
    __shared__ float bl_np[4][64];
    __shared__ unsigned char bl_sel[4][64];
    __shared__ int s_bstar[4];
    __shared__ unsigned int s_slot[4];

    const int tid = threadIdx.x;
    const int lane = tid & 63;
    const int wv = tid >> 6;
    const int row = blockIdx.x * 4 + wv;
    float* prow = po + (size_t)row * OUT_DIM;
    const float4* prow4 = (const float4*)prow;

    float4 r[16];
    float vmax = -1e30f;
    #pragma unroll
    for (int u = 0; u < 16; ++u) {
        r[u] = prow4[lane + 64 * u];
        vmax = fmaxf(vmax, fmaxf(fmaxf(r[u].x, r[u].y), fmaxf(r[u].z, r[u].w)));
    }
    #pragma unroll
    for (int off = 32; off > 0; off >>= 1)
        vmax = fmaxf(vmax, __shfl_xor(vmax, off));
    vmax = fmaxf(vmax, 1e-6f);
    const float scale = 256.0f / vmax;
    const float invscale = vmax * (1.0f / 256.0f);

    #pragma unroll
    for (int u = 0; u < 4; ++u) bins[wv][lane + 64 * u] = 0;
    if (lane == 0) { s_bstar[wv] = 0; s_slot[wv] = 0; }
    __syncthreads();
    #pragma unroll
    for (int u = 0; u < 16; ++u) {
        #pragma unroll
        for (int e = 0; e < 4; ++e) {
            float f = (e == 0) ? r[u].x : (e == 1) ? r[u].y
                    : (e == 2) ? r[u].z : r[u].w;
            if (f > 0.0f) {
                int b = (int)(f * scale);
                if (b > 255) b = 255;
                atomicAdd(&bins[wv][b], 1u);
            }
        }
    }
    __syncthreads();
    const int g = 63 - lane;
    const unsigned int c = bins[wv][4 * g] + bins[wv][4 * g + 1]
                         + bins[wv][4 * g + 2] + bins[wv][4 * g + 3];
    unsigned int sc = c;
    #pragma unroll
    for (int off = 1; off < 64; off <<= 1) {
        unsigned int t2 = __shfl_up(sc, off);
        if (lane >= off) sc += t2;
    }
    if ((int)sc >= K_TOP && (int)(sc - c) < K_TOP) {
        int cum = (int)(sc - c);
        int bstar = 4 * g;
        for (int bi = 4 * g + 3; bi >= 4 * g; --bi) {
            cum += (int)bins[wv][bi];
            if (cum >= K_TOP) { bstar = bi; break; }
        }
        s_bstar[wv] = bstar;
    }
    __syncthreads();
    const int bstar = s_bstar[wv];
    const float delta = 8e-3f;
    const float thi = (float)(bstar + 1) * invscale + delta;
    const float tlo = (float)bstar * invscale - delta;

    int hi = 0, nb = 0;
    #pragma unroll
    for (int u = 0; u < 16; ++u) {
        #pragma unroll
        for (int e = 0; e < 4; ++e) {
            float f = (e == 0) ? r[u].x : (e == 1) ? r[u].y
                    : (e == 2) ? r[u].z : r[u].w;
            bool isbl = (f <= thi) && (f >= tlo);
            hi += (int)__popcll(__ballot(f > thi));
            nb += (int)__popcll(__ballot(isbl));
            if (isbl) {
                unsigned int p = atomicAdd(&s_slot[wv], 1u);
                if (p < 64) bl_idx[wv][p] = (lane + 64 * u) * 4 + e;
            }
        }
    }
    int nbc = nb > 64 ? 64 : nb;
    int krem = K_TOP - hi; if (krem > nb) krem = nb; if (krem < 0) krem = 0;
    const bool need = (nb != krem);

    const int anyneed = __syncthreads_or(need ? 1 : 0);
    if (anyneed) {
        if (need) {
            const bool bipolar = (*flag == 0);
            const float4* xr4 = (const float4*)(x + (size_t)row * IN_DIM);
            #pragma unroll
            for (int u = 0; u < 4; ++u) {
                float4 xv = xr4[lane + 64 * u];
                if (bipolar) {
                    xv.x = __fmul_rn(__fadd_rn(xv.x, -0.5f), 2.0f);
                    xv.y = __fmul_rn(__fadd_rn(xv.y, -0.5f), 2.0f);
                    xv.z = __fmul_rn(__fadd_rn(xv.z, -0.5f), 2.0f);
                    xv.w = __fmul_rn(__fadd_rn(xv.w, -0.5f), 2.0f);
                }
                ((float4*)xs[wv])[lane + 64 * u] = xv;
            }
        }
        __syncthreads();
        if (need && lane < nbc) {
            const float4* wr4 = (const float4*)(w + (size_t)bl_idx[wv][lane] * IN_DIM);
            const float4* xs4 = (const float4*)xs[wv];
            float p = 0.0f;
            #pragma unroll 4
            for (int i = 0; i < IN_DIM / 4; ++i) {
                float4 xv = xs4[i];
                float4 wvv = wr4[i];
                p = __fmaf_rn(xv.x, wvv.x, p);
                p = __fmaf_rn(xv.y, wvv.y, p);
                p = __fmaf_rn(xv.z, wvv.z, p);
                p = __fmaf_rn(xv.w, wvv.w, p);
            }
            bl_np[wv][lane] = p;
        }
        __syncthreads();
        if (need && lane < nbc) {
            const float v = bl_np[wv][lane];
            int gcount = 0;
            for (int l = 0; l < nbc; ++l) gcount += (bl_np[wv][l] > v);
            bl_sel[wv][lane] = (gcount < krem) ? 1 : 0;
        }
        __syncthreads();
    }

    float nrm2 = 0.0f;
    #pragma unroll
    for (int u = 0; u < 16; ++u) {
        float4 o;
        #pragma unroll
        for (int e = 0; e < 4; ++e) {
            float f = (e == 0) ? r[u].x : (e == 1) ? r[u].y
                    : (e == 2) ? r[u].z : r[u].w;
            bool sel = (f > thi);
            float val = f;
            if (!sel && f >= tlo) {
                if (!need) sel = true;
                else {
                    const int j = (lane + 64 * u) * 4 + e;
                    sel = false;
                    for (int m = 0; m < nbc; ++m)
                        if (bl_idx[wv][m] == j) {
                            sel = (bl_sel[wv][m] != 0);
                            val = bl_np[wv][m];
                            break;
                        }
                }
            }
            float eo = (sel && val > 0.0f) ? val : 0.0f;
            if (e == 0) o.x = eo; else if (e == 1) o.y = eo;
            else if (e == 2) o.z = eo; else o.w = eo;
            nrm2 += eo * eo;
        }
        r[u] = o;
    }
    #pragma unroll
    for (int off = 32; off > 0; off >>= 1)
        nrm2 += __shfl_xor(nrm2, off);
    const float inv = 1.0f / fmaxf(sqrtf(nrm2), 1e-12f);
    #pragma unroll
    for (int u = 0; u < 16; ++u) {
        float4 e = r[u];
        e.x *= inv; e.y *= inv; e.z *= inv; e.w *= inv;
        ((float4*)prow)[lane + 64 * u] = e;
    }
}

// ---------------------------------------------------------------- launch
extern "C" void kernel_launch(void* const* d_in, const int* in_sizes, int n_in,
                              void* d_out, int out_size, void* d_ws, size_t ws_size,
                              hipStream_t stream) {
    const float* x = (const float*)d_in[0];
    const float* w = (const float*)d_in[1];
    float* out = (float*)d_out;
    int* flag = (int*)d_ws;

    hipMemsetAsync(flag, 0, sizeof(int), stream);
    k_hasneg<<<2048, 256, 0, stream>>>(x, BATCH * IN_DIM, flag);

    dim3 g(BATCH / 128, OUT_DIM / 128);
    if (ws_size >= WS_NEEDED) {
        _Float16* xh = (_Float16*)((char*)d_ws + WS_XH_OFF);
        _Float16* wh = (_Float16*)((char*)d_ws + WS_WH_OFF);
        k_cvt<<<2048, 256, 0, stream>>>(x, w, xh, wh, flag);
        k_gemm16<<<g, 256, 0, stream>>>(xh, wh, out);
    } else {
        k_gemm_fb<<<g, 256, 0, stream>>>(x, w, out, flag);
    }

    if (ws_size >= WS_NEED2) {
        float2* thr = (float2*)((char*)d_ws + WS_THR_OFF);
        int2*   cnt = (int2*)((char*)d_ws + WS_CNT_OFF);
        int*    rcol = (int*)((char*)d_ws + WS_COL_OFF);
        float*  rnp = (float*)((char*)d_ws + WS_NP_OFF);
        k_sel1<<<BATCH, 256, 0, stream>>>(out, thr, cnt, rcol);
        k_sel2<<<BATCH / 4, 256, 0, stream>>>(x, w, cnt, rcol, rnp, flag);
        k_sel3<<<BATCH, 256, 0, stream>>>(out, thr, cnt, rcol, rnp);
    } else {
        k_select_mono<<<BATCH / 4, 256, 0, stream>>>(out, x, w, flag);
    }
}

// Round 22
// 551.257 us; speedup vs baseline: 1.5471x; 1.3285x over previous
//
#include <hip/hip_runtime.h>

#define BATCH   16384
#define IN_DIM  1024
#define OUT_DIM 4096
#define K_TOP   409
#define DELTA_W 6.5e-3f

typedef _Float16 half8  __attribute__((ext_vector_type(8)));
typedef _Float16 half4v __attribute__((ext_vector_type(4)));
typedef float    f32x4  __attribute__((ext_vector_type(4)));

// workspace layout
#define WS_XH_OFF   256
#define WS_WH_OFF   (WS_XH_OFF + (size_t)BATCH * IN_DIM * 2)
#define WS_THR_OFF  (WS_WH_OFF + (size_t)OUT_DIM * IN_DIM * 2)
#define WS_CNT_OFF  (WS_THR_OFF + (size_t)BATCH * 8)
#define WS_COL_OFF  (WS_CNT_OFF + (size_t)BATCH * 8)
#define WS_NP_OFF   (WS_COL_OFF + (size_t)BATCH * 64 * 4)
#define WS_WV_OFF   (WS_NP_OFF + (size_t)BATCH * 64 * 4)
#define WS_WI_OFF   (WS_WV_OFF + (size_t)OUT_DIM * 256 * 4)
#define WS_WN_OFF   (WS_WI_OFF + (size_t)OUT_DIM * 256 * 2)
#define WS_NEEDED   (WS_WH_OFF + (size_t)OUT_DIM * IN_DIM * 2)
#define WS_NEED2    (WS_WV_OFF)
#define WS_NEED3    (WS_WN_OFF + (size_t)OUT_DIM * 4)

// ---------------------------------------------------------------- kernel A
__global__ __launch_bounds__(256)
void k_hasneg(const float* __restrict__ x, int n, int* __restrict__ flag) {
    const int stride = gridDim.x * blockDim.x;
    bool neg = false;
    for (int i = blockIdx.x * blockDim.x + threadIdx.x; i < n; i += stride)
        neg |= (x[i] < 0.0f);
    unsigned long long b = __ballot(neg);
    if (b != 0ULL && (threadIdx.x & 63) == 0)
        atomicOr(flag, 1);
}

// ---------------------------------------------------------------- kernel A2
__global__ __launch_bounds__(256)
void k_cvt(const float* __restrict__ x, const float* __restrict__ w,
           _Float16* __restrict__ xh, _Float16* __restrict__ wh,
           const int* __restrict__ flag) {
    const bool bipolar = (*flag == 0);
    const int stride = gridDim.x * blockDim.x;
    const int nx4 = BATCH * IN_DIM / 4;
    const int nw4 = OUT_DIM * IN_DIM / 4;
    for (int i = blockIdx.x * blockDim.x + threadIdx.x; i < nx4; i += stride) {
        float4 v = ((const float4*)x)[i];
        if (bipolar) {
            v.x = (v.x - 0.5f) * 2.0f; v.y = (v.y - 0.5f) * 2.0f;
            v.z = (v.z - 0.5f) * 2.0f; v.w = (v.w - 0.5f) * 2.0f;
        }
        ((half4v*)xh)[i] = half4v{ (_Float16)v.x, (_Float16)v.y,
                                   (_Float16)v.z, (_Float16)v.w };
    }
    for (int i = blockIdx.x * blockDim.x + threadIdx.x; i < nw4; i += stride) {
        float4 u = ((const float4*)w)[i];
        ((half4v*)wh)[i] = half4v{ (_Float16)u.x, (_Float16)u.y,
                                   (_Float16)u.z, (_Float16)u.w };
    }
}

// ---------------------------------------------------------------- kernel A3
// one-time CSR compression of w: nonzeros (values + u16 indices) per row,
// ASCENDING k order (preserves the reference chain order); zero-padded to
// multiple of 4 (fma with value 0 is a bitwise no-op on the accumulator).
__global__ __launch_bounds__(256)
void k_wcomp(const float* __restrict__ w, float* __restrict__ wv,
             unsigned short* __restrict__ wi, int* __restrict__ wn) {
    const int lane = threadIdx.x & 63;
    const int row = blockIdx.x * 4 + (threadIdx.x >> 6);
    const float* wr = w + (size_t)row * IN_DIM;
    const float4* wr4 = (const float4*)(wr + lane * 16);
    float4 v[4];
    int cnt = 0;
    #pragma unroll
    for (int q = 0; q < 4; ++q) {
        v[q] = wr4[q];
        cnt += (v[q].x != 0.0f) + (v[q].y != 0.0f)
             + (v[q].z != 0.0f) + (v[q].w != 0.0f);
    }
    int off = cnt;
    #pragma unroll
    for (int d = 1; d < 64; d <<= 1) {
        int t = __shfl_up(off, d);
        if (lane >= d) off += t;
    }
    const int total = __shfl(off, 63);
    off -= cnt;                       // exclusive prefix
    float* dv = wv + (size_t)row * 256;
    unsigned short* di = wi + (size_t)row * 256;
    int pos = off;
    #pragma unroll
    for (int q = 0; q < 4; ++q) {
        #pragma unroll
        for (int e = 0; e < 4; ++e) {
            float f = (e == 0) ? v[q].x : (e == 1) ? v[q].y
                    : (e == 2) ? v[q].z : v[q].w;
            if (f != 0.0f) {
                dv[pos] = f;
                di[pos] = (unsigned short)(lane * 16 + q * 4 + e);
                ++pos;
            }
        }
    }
    if (lane == 0) {
        const int n4 = (total + 3) & ~3;
        for (int i = total; i < n4 && i < 256; ++i) { dv[i] = 0.0f; di[i] = 0; }
        wn[row] = total;
    }
}

// ---------------------------------------------------------------- kernel B
// (r16-proven: global_load_lds w16, pre-swizzled source, 0 bank conflicts)
__global__ __launch_bounds__(256)
void k_gemm16(const _Float16* __restrict__ xh, const _Float16* __restrict__ wh,
              float* __restrict__ out) {
    __shared__ _Float16 Ah[128 * 64];
    __shared__ _Float16 Bh[128 * 64];
    const int tid = threadIdx.x;
    const int bm = blockIdx.x, bn = blockIdx.y;
    const int lane = tid & 63;
    const int wv = tid >> 6;
    const int wm = wv >> 1, wn = wv & 1;
    const int lr = lane & 15, lk = lane >> 4;

    const int srow = (lane >> 3);
    const int sslot = (lane & 7) ^ srow;
    f32x4 acc[4][4] = {};

    const _Float16* aS[4]; const _Float16* bS[4];
    _Float16* aD[4]; _Float16* bD[4];
    #pragma unroll
    for (int i = 0; i < 4; ++i) {
        const int rb = i * 32 + wv * 8;
        aS[i] = xh + (size_t)(bm * 128 + rb + srow) * IN_DIM + sslot * 8;
        bS[i] = wh + (size_t)(bn * 128 + rb + srow) * IN_DIM + sslot * 8;
        aD[i] = &Ah[rb * 64];
        bD[i] = &Bh[rb * 64];
    }

    #pragma unroll 1
    for (int kt = 0; kt < IN_DIM; kt += 64) {
        __syncthreads();
        #pragma unroll
        for (int i = 0; i < 4; ++i) {
            __builtin_amdgcn_global_load_lds((const __attribute__((address_space(1))) void*)(aS[i] + kt), (__attribute__((address_space(3))) void*)aD[i], 16, 0, 0);
            __builtin_amdgcn_global_load_lds((const __attribute__((address_space(1))) void*)(bS[i] + kt), (__attribute__((address_space(3))) void*)bD[i], 16, 0, 0);
        }
        __syncthreads();
        #pragma unroll
        for (int h = 0; h < 2; ++h) {
            half8 af[4], bf[4];
            #pragma unroll
            for (int i = 0; i < 4; ++i) {
                const int ra = wm * 64 + i * 16 + lr;
                const int sa = (h * 4 + lk) ^ (ra & 7);
                af[i] = *(const half8*)&Ah[ra * 64 + (sa << 3)];
                const int rb = wn * 64 + i * 16 + lr;
                const int sb = (h * 4 + lk) ^ (rb & 7);
                bf[i] = *(const half8*)&Bh[rb * 64 + (sb << 3)];
            }
            #pragma unroll
            for (int i = 0; i < 4; ++i)
                #pragma unroll
                for (int j = 0; j < 4; ++j)
                    acc[i][j] = __builtin_amdgcn_mfma_f32_16x16x32_f16(
                        af[i], bf[j], acc[i][j], 0, 0, 0);
        }
    }
    #pragma unroll
    for (int i = 0; i < 4; ++i)
        #pragma unroll
        for (int j = 0; j < 4; ++j)
            #pragma unroll
            for (int q = 0; q < 4; ++q) {
                const int row = bm * 128 + wm * 64 + i * 16 + lk * 4 + q;
                const int col = bn * 128 + wn * 64 + j * 16 + lr;
                out[(size_t)row * OUT_DIM + col] = acc[i][j][q];
            }
}

// ---------------------------------------------------------------- kernel C1
// per row: vmax, pass-1 256-bin histogram -> boundary bucket; pass-2 256
// sub-bin refinement inside the bucket -> boundary to vmax/65536; window
// = sub-bucket +- DELTA_W; classify, records, meta.
__global__ __launch_bounds__(256)
void k_sel1(const float* __restrict__ po, float2* __restrict__ thr,
            int2* __restrict__ cnt, int* __restrict__ rcol) {
    __shared__ unsigned int bins[256];
    __shared__ float fred[4];
    __shared__ unsigned int wsum[4];
    __shared__ int s_b, s_b2;
    __shared__ unsigned int s_hi, s_slot, s_hi1;
    const int row = blockIdx.x;
    const int tid = threadIdx.x;
    const int lane = tid & 63, wq = tid >> 6;
    const float4* p4 = (const float4*)(po + (size_t)row * OUT_DIM);

    float4 rv[4];
    float vmax = -1e30f;
    #pragma unroll
    for (int u = 0; u < 4; ++u) {
        rv[u] = p4[tid + 256 * u];
        vmax = fmaxf(vmax, fmaxf(fmaxf(rv[u].x, rv[u].y), fmaxf(rv[u].z, rv[u].w)));
    }
    #pragma unroll
    for (int off = 32; off > 0; off >>= 1)
        vmax = fmaxf(vmax, __shfl_xor(vmax, off));
    if (lane == 0) fred[wq] = vmax;
    bins[tid] = 0;
    if (tid == 0) { s_hi = 0; s_slot = 0; s_b = 0; s_b2 = 0; s_hi1 = 0; }
    __syncthreads();
    vmax = fmaxf(fmaxf(fmaxf(fred[0], fred[1]), fmaxf(fred[2], fred[3])), 1e-6f);
    const float scale1 = 256.0f / vmax;
    const float invscale1 = vmax * (1.0f / 256.0f);

    // pass 1
    #pragma unroll
    for (int u = 0; u < 4; ++u) {
        #pragma unroll
        for (int e = 0; e < 4; ++e) {
            float f = (e == 0) ? rv[u].x : (e == 1) ? rv[u].y
                    : (e == 2) ? rv[u].z : rv[u].w;
            if (f > 0.0f) {
                int b = (int)(f * scale1);
                if (b > 255) b = 255;
                atomicAdd(&bins[b], 1u);
            }
        }
    }
    __syncthreads();
    {
        const unsigned int c = bins[255 - tid];
        unsigned int sc = c;
        #pragma unroll
        for (int off = 1; off < 64; off <<= 1) {
            unsigned int t2 = __shfl_up(sc, off);
            if (lane >= off) sc += t2;
        }
        if (lane == 63) wsum[wq] = sc;
        __syncthreads();
        for (int q = 0; q < wq; ++q) sc += wsum[q];
        if ((int)sc >= K_TOP && (int)(sc - c) < K_TOP) {
            s_b = 255 - tid;
            s_hi1 = sc - c;              // count strictly above bucket
        }
    }
    __syncthreads();
    const int b1 = s_b;
    const unsigned int hi1 = s_hi1;
    const float blo = (float)b1 * invscale1;
    const float scale2 = scale1 * 256.0f;
    const float s2w = invscale1 * (1.0f / 256.0f);

    // pass 2: re-zero, sub-histogram of the boundary bucket
    bins[tid] = 0;
    __syncthreads();
    #pragma unroll
    for (int u = 0; u < 4; ++u) {
        #pragma unroll
        for (int e = 0; e < 4; ++e) {
            float f = (e == 0) ? rv[u].x : (e == 1) ? rv[u].y
                    : (e == 2) ? rv[u].z : rv[u].w;
            if (f > 0.0f) {
                int b = (int)(f * scale1);
                if (b > 255) b = 255;
                if (b == b1) {
                    int b2 = (int)((f - blo) * scale2);
                    if (b2 < 0) b2 = 0;
                    if (b2 > 255) b2 = 255;
                    atomicAdd(&bins[b2], 1u);
                }
            }
        }
    }
    __syncthreads();
    {
        const unsigned int c = bins[255 - tid];
        unsigned int sc = c;
        #pragma unroll
        for (int off = 1; off < 64; off <<= 1) {
            unsigned int t2 = __shfl_up(sc, off);
            if (lane >= off) sc += t2;
        }
        if (lane == 63) wsum[wq] = sc;
        __syncthreads();
        for (int q = 0; q < wq; ++q) sc += wsum[q];
        if ((int)(hi1 + sc) >= K_TOP && (int)(hi1 + sc - c) < K_TOP)
            s_b2 = 255 - tid;
    }
    __syncthreads();
    const float thi = blo + (float)(s_b2 + 1) * s2w + DELTA_W;
    const float tlo = blo + (float)s_b2 * s2w - DELTA_W;

    // classify
    #pragma unroll
    for (int u = 0; u < 4; ++u) {
        #pragma unroll
        for (int e = 0; e < 4; ++e) {
            float f = (e == 0) ? rv[u].x : (e == 1) ? rv[u].y
                    : (e == 2) ? rv[u].z : rv[u].w;
            if (f > thi) atomicAdd(&s_hi, 1u);
            else if (f >= tlo) {
                unsigned int p = atomicAdd(&s_slot, 1u);
                if (p < 64) rcol[row * 64 + p] = (tid + 256 * u) * 4 + e;
            }
        }
    }
    __syncthreads();
    if (tid == 0) {
        int nb = (int)s_slot;
        int krem = K_TOP - (int)s_hi;
        if (krem > nb) krem = nb;
        if (krem < 0) krem = 0;
        thr[row] = make_float2(thi, tlo);
        cnt[row] = make_int2(nb, krem);
    }
}

// ---------------------------------------------------------------- kernel C2
// compressed replica: 4 rows/block, wave per row, record per lane. x row
// staged bipolar into LDS once; chain = fma over w's NONZEROS in ascending
// k order (bitwise identical to the full r13 chain: fma with 0 is a no-op
// on the accumulator; pad entries have value 0).
__global__ __launch_bounds__(256)
void k_sel2(const float* __restrict__ x, const float* __restrict__ wvals,
            const unsigned short* __restrict__ widx, const int* __restrict__ wn,
            const int2* __restrict__ cnt, const int* __restrict__ rcol,
            float* __restrict__ rnp, const int* __restrict__ flag) {
    __shared__ float xs[4][IN_DIM];
    const int tid = threadIdx.x;
    const int lane = tid & 63;
    const int wv = tid >> 6;
    const int row = blockIdx.x * 4 + wv;
    const bool bipolar = (*flag == 0);

    const float4* xr4 = (const float4*)(x + (size_t)row * IN_DIM);
    #pragma unroll
    for (int u = 0; u < 4; ++u) {
        float4 xv = xr4[lane + 64 * u];
        if (bipolar) {
            xv.x = __fmul_rn(__fadd_rn(xv.x, -0.5f), 2.0f);
            xv.y = __fmul_rn(__fadd_rn(xv.y, -0.5f), 2.0f);
            xv.z = __fmul_rn(__fadd_rn(xv.z, -0.5f), 2.0f);
            xv.w = __fmul_rn(__fadd_rn(xv.w, -0.5f), 2.0f);
        }
        ((float4*)xs[wv])[lane + 64 * u] = xv;
    }
    __syncthreads();

    int nb = cnt[row].x; if (nb > 64) nb = 64;
    if (lane < nb) {
        const int col = rcol[row * 64 + lane];
        const int n4 = (wn[col] + 3) >> 2;
        const float4* v4 = (const float4*)(wvals + (size_t)col * 256);
        const ushort4* i4 = (const ushort4*)(widx + (size_t)col * 256);
        const float* xr = xs[wv];
        float p = 0.0f;
        #pragma unroll 2
        for (int i = 0; i < n4; ++i) {
            float4 vv = v4[i];
            ushort4 ii = i4[i];
            p = __fmaf_rn(xr[ii.x], vv.x, p);
            p = __fmaf_rn(xr[ii.y], vv.y, p);
            p = __fmaf_rn(xr[ii.z], vv.z, p);
            p = __fmaf_rn(xr[ii.w], vv.w, p);
        }
        rnp[row * 64 + lane] = p;
    }
}

// ---------------------------------------------------------------- kernel C2'
// fallback (r21-proven): full 1024-chain per record
__global__ __launch_bounds__(256)
void k_sel2_full(const float* __restrict__ x, const float* __restrict__ w,
                 const int2* __restrict__ cnt, const int* __restrict__ rcol,
                 float* __restrict__ rnp, const int* __restrict__ flag) {
    __shared__ float xs[4][IN_DIM];
    const int tid = threadIdx.x;
    const int lane = tid & 63;
    const int wv = tid >> 6;
    const int row = blockIdx.x * 4 + wv;
    const bool bipolar = (*flag == 0);

    const float4* xr4 = (const float4*)(x + (size_t)row * IN_DIM);
    #pragma unroll
    for (int u = 0; u < 4; ++u) {
        float4 xv = xr4[lane + 64 * u];
        if (bipolar) {
            xv.x = __fmul_rn(__fadd_rn(xv.x, -0.5f), 2.0f);
            xv.y = __fmul_rn(__fadd_rn(xv.y, -0.5f), 2.0f);
            xv.z = __fmul_rn(__fadd_rn(xv.z, -0.5f), 2.0f);
            xv.w = __fmul_rn(__fadd_rn(xv.w, -0.5f), 2.0f);
        }
        ((float4*)xs[wv])[lane + 64 * u] = xv;
    }
    __syncthreads();

    int nb = cnt[row].x; if (nb > 64) nb = 64;
    if (lane < nb) {
        const int col = rcol[row * 64 + lane];
        const float4* wr4 = (const float4*)(w + (size_t)col * IN_DIM);
        const float4* xs4 = (const float4*)xs[wv];
        float p = 0.0f;
        #pragma unroll 4
        for (int i = 0; i < IN_DIM / 4; ++i) {
            float4 xv = xs4[i];
            float4 wvv = wr4[i];
            p = __fmaf_rn(xv.x, wvv.x, p);
            p = __fmaf_rn(xv.y, wvv.y, p);
            p = __fmaf_rn(xv.z, wvv.z, p);
            p = __fmaf_rn(xv.w, wvv.w, p);
        }
        rnp[row * 64 + lane] = p;
    }
}

// ---------------------------------------------------------------- kernel C3
__global__ __launch_bounds__(256)
void k_sel3(float* __restrict__ po, const float2* __restrict__ thr,
            const int2* __restrict__ cnt, const int* __restrict__ rcol,
            const float* __restrict__ rnp) {
    __shared__ int bcol[64];
    __shared__ float bnp[64];
    __shared__ unsigned char bsel[64];
    __shared__ float fred[4];
    const int row = blockIdx.x;
    const int tid = threadIdx.x;
    const int lane = tid & 63, wq = tid >> 6;
    const float2 th = thr[row];
    const int2 cn = cnt[row];
    const float thi = th.x, tlo = th.y;
    const int nb = cn.x, krem = cn.y;
    const int nbc = nb > 64 ? 64 : nb;
    const bool need = (nb != krem);

    if (tid < nbc) { bcol[tid] = rcol[row * 64 + tid]; bnp[tid] = rnp[row * 64 + tid]; }
    __syncthreads();
    if (tid < nbc) {
        const float v = bnp[tid];
        int gc = 0;
        for (int l = 0; l < nbc; ++l) gc += (bnp[l] > v);
        bsel[tid] = (gc < krem) ? 1 : 0;
    }
    __syncthreads();

    float4* p4 = (float4*)(po + (size_t)row * OUT_DIM);
    float4 rv[4];
    float nrm2 = 0.0f;
    #pragma unroll
    for (int u = 0; u < 4; ++u) {
        float4 v = p4[tid + 256 * u];
        float4 o;
        #pragma unroll
        for (int e = 0; e < 4; ++e) {
            float f = (e == 0) ? v.x : (e == 1) ? v.y : (e == 2) ? v.z : v.w;
            bool sel = (f > thi);
            float val = f;
            if (!sel && f >= tlo) {
                if (!need) sel = true;
                else {
                    const int j = (tid + 256 * u) * 4 + e;
                    for (int m = 0; m < nbc; ++m)
                        if (bcol[m] == j) {
                            sel = (bsel[m] != 0);
                            val = bnp[m];
                            break;
                        }
                }
            }
            float eo = (sel && val > 0.0f) ? val : 0.0f;
            if (e == 0) o.x = eo; else if (e == 1) o.y = eo;
            else if (e == 2) o.z = eo; else o.w = eo;
            nrm2 += eo * eo;
        }
        rv[u] = o;
    }
    #pragma unroll
    for (int off = 32; off > 0; off >>= 1)
        nrm2 += __shfl_xor(nrm2, off);
    if (lane == 0) fred[wq] = nrm2;
    __syncthreads();
    const float total = fred[0] + fred[1] + fred[2] + fred[3];
    const float inv = 1.0f / fmaxf(sqrtf(total), 1e-12f);
    #pragma unroll
    for (int u = 0; u < 4; ++u) {
        float4 e = rv[u];
        e.x *= inv; e.y *= inv; e.z *= inv; e.w *= inv;
        p4[tid + 256 * u] = e;
    }
}

// ---------------------------------------------------------------- launch
extern "C" void kernel_launch(void* const* d_in, const int* in_sizes, int n_in,
                              void* d_out, int out_size, void* d_ws, size_t ws_size,
                              hipStream_t stream) {
    const float* x = (const float*)d_in[0];
    const float* w = (const float*)d_in[1];
    float* out = (float*)d_out;
    int* flag = (int*)d_ws;

    hipMemsetAsync(flag, 0, sizeof(int), stream);
    k_hasneg<<<2048, 256, 0, stream>>>(x, BATCH * IN_DIM, flag);

    dim3 g(BATCH / 128, OUT_DIM / 128);
    _Float16* xh = (_Float16*)((char*)d_ws + WS_XH_OFF);
    _Float16* wh = (_Float16*)((char*)d_ws + WS_WH_OFF);
    k_cvt<<<2048, 256, 0, stream>>>(x, w, xh, wh, flag);
    k_gemm16<<<g, 256, 0, stream>>>(xh, wh, out);

    float2* thr = (float2*)((char*)d_ws + WS_THR_OFF);
    int2*   cnt = (int2*)((char*)d_ws + WS_CNT_OFF);
    int*    rcol = (int*)((char*)d_ws + WS_COL_OFF);
    float*  rnp = (float*)((char*)d_ws + WS_NP_OFF);
    k_sel1<<<BATCH, 256, 0, stream>>>(out, thr, cnt, rcol);
    if (ws_size >= WS_NEED3) {
        float* wv = (float*)((char*)d_ws + WS_WV_OFF);
        unsigned short* wi = (unsigned short*)((char*)d_ws + WS_WI_OFF);
        int* wn = (int*)((char*)d_ws + WS_WN_OFF);
        k_wcomp<<<OUT_DIM / 4, 256, 0, stream>>>(w, wv, wi, wn);
        k_sel2<<<BATCH / 4, 256, 0, stream>>>(x, wv, wi, wn, cnt, rcol, rnp, flag);
    } else {
        k_sel2_full<<<BATCH / 4, 256, 0, stream>>>(x, w, cnt, rcol, rnp, flag);
    }
    k_sel3<<<BATCH, 256, 0, stream>>>(out, thr, cnt, rcol, rnp);
}

// Round 23
// 460.662 us; speedup vs baseline: 1.8513x; 1.1967x over previous
//
#include <hip/hip_runtime.h>

#define BATCH   16384
#define IN_DIM  1024
#define OUT_DIM 4096
#define K_TOP   409
#define DELTA_W 6.5e-3f

typedef _Float16 half8  __attribute__((ext_vector_type(8)));
typedef _Float16 half4v __attribute__((ext_vector_type(4)));
typedef float    f32x4  __attribute__((ext_vector_type(4)));

// workspace layout
#define WS_XH_OFF   256
#define WS_WH_OFF   (WS_XH_OFF + (size_t)BATCH * IN_DIM * 2)
#define WS_THR_OFF  (WS_WH_OFF + (size_t)OUT_DIM * IN_DIM * 2)
#define WS_CNT_OFF  (WS_THR_OFF + (size_t)BATCH * 8)
#define WS_COL_OFF  (WS_CNT_OFF + (size_t)BATCH * 8)
#define WS_NP_OFF   (WS_COL_OFF + (size_t)BATCH * 64 * 4)
#define WS_WV_OFF   (WS_NP_OFF + (size_t)BATCH * 64 * 4)
#define WS_WI_OFF   (WS_WV_OFF + (size_t)OUT_DIM * 256 * 4)
#define WS_WN_OFF   (WS_WI_OFF + (size_t)OUT_DIM * 256 * 2)
#define WS_NEEDED   (WS_WH_OFF + (size_t)OUT_DIM * IN_DIM * 2)
#define WS_NEED3    (WS_WN_OFF + (size_t)OUT_DIM * 4)

// fast values are stored as f16 packed in the FIRST 8KB of each row's 16KB
// f32 slot in d_out: f16 row i base = (char*)out + i*OUT_DIM*4.

// ---------------------------------------------------------------- kernel A
__global__ __launch_bounds__(256)
void k_hasneg(const float* __restrict__ x, int n, int* __restrict__ flag) {
    const int stride = gridDim.x * blockDim.x;
    bool neg = false;
    for (int i = blockIdx.x * blockDim.x + threadIdx.x; i < n; i += stride)
        neg |= (x[i] < 0.0f);
    unsigned long long b = __ballot(neg);
    if (b != 0ULL && (threadIdx.x & 63) == 0)
        atomicOr(flag, 1);
}

// ---------------------------------------------------------------- kernel A2
__global__ __launch_bounds__(256)
void k_cvt(const float* __restrict__ x, const float* __restrict__ w,
           _Float16* __restrict__ xh, _Float16* __restrict__ wh,
           const int* __restrict__ flag) {
    const bool bipolar = (*flag == 0);
    const int stride = gridDim.x * blockDim.x;
    const int nx4 = BATCH * IN_DIM / 4;
    const int nw4 = OUT_DIM * IN_DIM / 4;
    for (int i = blockIdx.x * blockDim.x + threadIdx.x; i < nx4; i += stride) {
        float4 v = ((const float4*)x)[i];
        if (bipolar) {
            v.x = (v.x - 0.5f) * 2.0f; v.y = (v.y - 0.5f) * 2.0f;
            v.z = (v.z - 0.5f) * 2.0f; v.w = (v.w - 0.5f) * 2.0f;
        }
        ((half4v*)xh)[i] = half4v{ (_Float16)v.x, (_Float16)v.y,
                                   (_Float16)v.z, (_Float16)v.w };
    }
    for (int i = blockIdx.x * blockDim.x + threadIdx.x; i < nw4; i += stride) {
        float4 u = ((const float4*)w)[i];
        ((half4v*)wh)[i] = half4v{ (_Float16)u.x, (_Float16)u.y,
                                   (_Float16)u.z, (_Float16)u.w };
    }
}

// ---------------------------------------------------------------- kernel A3
// one-time CSR compression of w (ascending k, zero-padded to x4).
__global__ __launch_bounds__(256)
void k_wcomp(const float* __restrict__ w, float* __restrict__ wv,
             unsigned short* __restrict__ wi, int* __restrict__ wn) {
    const int lane = threadIdx.x & 63;
    const int row = blockIdx.x * 4 + (threadIdx.x >> 6);
    const float* wr = w + (size_t)row * IN_DIM;
    const float4* wr4 = (const float4*)(wr + lane * 16);
    float4 v[4];
    int cnt = 0;
    #pragma unroll
    for (int q = 0; q < 4; ++q) {
        v[q] = wr4[q];
        cnt += (v[q].x != 0.0f) + (v[q].y != 0.0f)
             + (v[q].z != 0.0f) + (v[q].w != 0.0f);
    }
    int off = cnt;
    #pragma unroll
    for (int d = 1; d < 64; d <<= 1) {
        int t = __shfl_up(off, d);
        if (lane >= d) off += t;
    }
    const int total = __shfl(off, 63);
    off -= cnt;
    float* dv = wv + (size_t)row * 256;
    unsigned short* di = wi + (size_t)row * 256;
    int pos = off;
    #pragma unroll
    for (int q = 0; q < 4; ++q) {
        #pragma unroll
        for (int e = 0; e < 4; ++e) {
            float f = (e == 0) ? v[q].x : (e == 1) ? v[q].y
                    : (e == 2) ? v[q].z : v[q].w;
            if (f != 0.0f) {
                dv[pos] = f;
                di[pos] = (unsigned short)(lane * 16 + q * 4 + e);
                ++pos;
            }
        }
    }
    if (lane == 0) {
        const int n4 = (total + 3) & ~3;
        for (int i = total; i < n4 && i < 256; ++i) { dv[i] = 0.0f; di[i] = 0; }
        wn[row] = total;
    }
}

// ---------------------------------------------------------------- kernel B
// 2-phase double-buffered MFMA GEMM (T3-minimal): issue next tile's
// global_load_lds into buf^1 BEFORE computing current tile from buf; one
// barrier per K-step (its vmcnt drain lands the prefetch). Fragment layout,
// pre-swizzled source + XOR LDS read swizzle identical to r16 (0 conflicts).
// Output: f16 fast values packed into each row's f32 slot.
__global__ __launch_bounds__(256)
void k_gemm16(const _Float16* __restrict__ xh, const _Float16* __restrict__ wh,
              float* __restrict__ out) {
    __shared__ _Float16 Ah[2][128 * 64];
    __shared__ _Float16 Bh[2][128 * 64];
    const int tid = threadIdx.x;
    const int bm = blockIdx.x, bn = blockIdx.y;
    const int lane = tid & 63;
    const int wv = tid >> 6;
    const int wm = wv >> 1, wn = wv & 1;
    const int lr = lane & 15, lk = lane >> 4;

    const int srow = (lane >> 3);
    const int sslot = (lane & 7) ^ srow;
    f32x4 acc[4][4] = {};

    const _Float16* aS[4]; const _Float16* bS[4];
    int dOff[4];
    #pragma unroll
    for (int i = 0; i < 4; ++i) {
        const int rb = i * 32 + wv * 8;
        aS[i] = xh + (size_t)(bm * 128 + rb + srow) * IN_DIM + sslot * 8;
        bS[i] = wh + (size_t)(bn * 128 + rb + srow) * IN_DIM + sslot * 8;
        dOff[i] = rb * 64;
    }

    // prologue: stage tile 0 into buf 0
    #pragma unroll
    for (int i = 0; i < 4; ++i) {
        __builtin_amdgcn_global_load_lds((const __attribute__((address_space(1))) void*)(aS[i]), (__attribute__((address_space(3))) void*)&Ah[0][dOff[i]], 16, 0, 0);
        __builtin_amdgcn_global_load_lds((const __attribute__((address_space(1))) void*)(bS[i]), (__attribute__((address_space(3))) void*)&Bh[0][dOff[i]], 16, 0, 0);
    }
    __syncthreads();

    int cur = 0;
    #pragma unroll 1
    for (int t = 0; t < 16; ++t) {
        if (t < 15) {                 // prefetch next tile into buf^1
            const int kt = (t + 1) * 64;
            #pragma unroll
            for (int i = 0; i < 4; ++i) {
                __builtin_amdgcn_global_load_lds((const __attribute__((address_space(1))) void*)(aS[i] + kt), (__attribute__((address_space(3))) void*)&Ah[cur ^ 1][dOff[i]], 16, 0, 0);
                __builtin_amdgcn_global_load_lds((const __attribute__((address_space(1))) void*)(bS[i] + kt), (__attribute__((address_space(3))) void*)&Bh[cur ^ 1][dOff[i]], 16, 0, 0);
            }
        }
        #pragma unroll
        for (int h = 0; h < 2; ++h) {
            half8 af[4], bf[4];
            #pragma unroll
            for (int i = 0; i < 4; ++i) {
                const int ra = wm * 64 + i * 16 + lr;
                const int sa = (h * 4 + lk) ^ (ra & 7);
                af[i] = *(const half8*)&Ah[cur][ra * 64 + (sa << 3)];
                const int rb = wn * 64 + i * 16 + lr;
                const int sb = (h * 4 + lk) ^ (rb & 7);
                bf[i] = *(const half8*)&Bh[cur][rb * 64 + (sb << 3)];
            }
            #pragma unroll
            for (int i = 0; i < 4; ++i)
                #pragma unroll
                for (int j = 0; j < 4; ++j)
                    acc[i][j] = __builtin_amdgcn_mfma_f32_16x16x32_f16(
                        af[i], bf[j], acc[i][j], 0, 0, 0);
        }
        __syncthreads();              // drains prefetch + ends reads of cur
        cur ^= 1;
    }
    // epilogue: f16 store into each row's f32 slot
    #pragma unroll
    for (int i = 0; i < 4; ++i)
        #pragma unroll
        for (int j = 0; j < 4; ++j)
            #pragma unroll
            for (int q = 0; q < 4; ++q) {
                const int row = bm * 128 + wm * 64 + i * 16 + lk * 4 + q;
                const int col = bn * 128 + wn * 64 + j * 16 + lr;
                _Float16* fo = (_Float16*)((char*)out + (size_t)row * OUT_DIM * 4);
                fo[col] = (_Float16)acc[i][j][q];
            }
}

// ---------------------------------------------------------------- kernel C1
// per row (f16 fast values): vmax, 2-level 256-bin histogram -> boundary
// sub-bucket; window +- DELTA_W; classify, records, meta.
__global__ __launch_bounds__(256)
void k_sel1(const float* __restrict__ po, float2* __restrict__ thr,
            int2* __restrict__ cnt, int* __restrict__ rcol) {
    __shared__ unsigned int bins[256];
    __shared__ float fred[4];
    __shared__ unsigned int wsum[4];
    __shared__ int s_b, s_b2;
    __shared__ unsigned int s_hi, s_slot, s_hi1;
    const int row = blockIdx.x;
    const int tid = threadIdx.x;
    const int lane = tid & 63, wq = tid >> 6;
    const _Float16* fr = (const _Float16*)((const char*)po + (size_t)row * OUT_DIM * 4);

    half8 h0 = *(const half8*)&fr[tid * 8];
    half8 h1 = *(const half8*)&fr[2048 + tid * 8];
    float fv[16];
    float vmax = -1e30f;
    #pragma unroll
    for (int e = 0; e < 8; ++e) {
        fv[e] = (float)h0[e];
        fv[8 + e] = (float)h1[e];
        vmax = fmaxf(vmax, fmaxf(fv[e], fv[8 + e]));
    }
    #pragma unroll
    for (int off = 32; off > 0; off >>= 1)
        vmax = fmaxf(vmax, __shfl_xor(vmax, off));
    if (lane == 0) fred[wq] = vmax;
    bins[tid] = 0;
    if (tid == 0) { s_hi = 0; s_slot = 0; s_b = 0; s_b2 = 0; s_hi1 = 0; }
    __syncthreads();
    vmax = fmaxf(fmaxf(fmaxf(fred[0], fred[1]), fmaxf(fred[2], fred[3])), 1e-6f);
    const float scale1 = 256.0f / vmax;
    const float invscale1 = vmax * (1.0f / 256.0f);

    // pass 1
    #pragma unroll
    for (int e = 0; e < 16; ++e) {
        float f = fv[e];
        if (f > 0.0f) {
            int b = (int)(f * scale1);
            if (b > 255) b = 255;
            atomicAdd(&bins[b], 1u);
        }
    }
    __syncthreads();
    {
        const unsigned int c = bins[255 - tid];
        unsigned int sc = c;
        #pragma unroll
        for (int off = 1; off < 64; off <<= 1) {
            unsigned int t2 = __shfl_up(sc, off);
            if (lane >= off) sc += t2;
        }
        if (lane == 63) wsum[wq] = sc;
        __syncthreads();
        for (int q = 0; q < wq; ++q) sc += wsum[q];
        if ((int)sc >= K_TOP && (int)(sc - c) < K_TOP) {
            s_b = 255 - tid;
            s_hi1 = sc - c;
        }
    }
    __syncthreads();
    const int b1 = s_b;
    const unsigned int hi1 = s_hi1;
    const float blo = (float)b1 * invscale1;
    const float scale2 = scale1 * 256.0f;
    const float s2w = invscale1 * (1.0f / 256.0f);

    bins[tid] = 0;
    __syncthreads();
    #pragma unroll
    for (int e = 0; e < 16; ++e) {
        float f = fv[e];
        if (f > 0.0f) {
            int b = (int)(f * scale1);
            if (b > 255) b = 255;
            if (b == b1) {
                int b2 = (int)((f - blo) * scale2);
                if (b2 < 0) b2 = 0;
                if (b2 > 255) b2 = 255;
                atomicAdd(&bins[b2], 1u);
            }
        }
    }
    __syncthreads();
    {
        const unsigned int c = bins[255 - tid];
        unsigned int sc = c;
        #pragma unroll
        for (int off = 1; off < 64; off <<= 1) {
            unsigned int t2 = __shfl_up(sc, off);
            if (lane >= off) sc += t2;
        }
        if (lane == 63) wsum[wq] = sc;
        __syncthreads();
        for (int q = 0; q < wq; ++q) sc += wsum[q];
        if ((int)(hi1 + sc) >= K_TOP && (int)(hi1 + sc - c) < K_TOP)
            s_b2 = 255 - tid;
    }
    __syncthreads();
    const float thi = blo + (float)(s_b2 + 1) * s2w + DELTA_W;
    const float tlo = blo + (float)s_b2 * s2w - DELTA_W;

    #pragma unroll
    for (int e = 0; e < 16; ++e) {
        float f = fv[e];
        if (f > thi) atomicAdd(&s_hi, 1u);
        else if (f >= tlo) {
            unsigned int p = atomicAdd(&s_slot, 1u);
            const int j = (e < 8) ? (tid * 8 + e) : (2048 + tid * 8 + e - 8);
            if (p < 64) rcol[row * 64 + p] = j;
        }
    }
    __syncthreads();
    if (tid == 0) {
        int nb = (int)s_slot;
        int krem = K_TOP - (int)s_hi;
        if (krem > nb) krem = nb;
        if (krem < 0) krem = 0;
        thr[row] = make_float2(thi, tlo);
        cnt[row] = make_int2(nb, krem);
    }
}

// ---------------------------------------------------------------- kernel C2
// compressed replica (r22-proven): bitwise-exact r13 chain over w nonzeros.
__global__ __launch_bounds__(256)
void k_sel2(const float* __restrict__ x, const float* __restrict__ wvals,
            const unsigned short* __restrict__ widx, const int* __restrict__ wn,
            const int2* __restrict__ cnt, const int* __restrict__ rcol,
            float* __restrict__ rnp, const int* __restrict__ flag) {
    __shared__ float xs[4][IN_DIM];
    const int tid = threadIdx.x;
    const int lane = tid & 63;
    const int wv = tid >> 6;
    const int row = blockIdx.x * 4 + wv;
    const bool bipolar = (*flag == 0);

    const float4* xr4 = (const float4*)(x + (size_t)row * IN_DIM);
    #pragma unroll
    for (int u = 0; u < 4; ++u) {
        float4 xv = xr4[lane + 64 * u];
        if (bipolar) {
            xv.x = __fmul_rn(__fadd_rn(xv.x, -0.5f), 2.0f);
            xv.y = __fmul_rn(__fadd_rn(xv.y, -0.5f), 2.0f);
            xv.z = __fmul_rn(__fadd_rn(xv.z, -0.5f), 2.0f);
            xv.w = __fmul_rn(__fadd_rn(xv.w, -0.5f), 2.0f);
        }
        ((float4*)xs[wv])[lane + 64 * u] = xv;
    }
    __syncthreads();

    int nb = cnt[row].x; if (nb > 64) nb = 64;
    if (lane < nb) {
        const int col = rcol[row * 64 + lane];
        const int n4 = (wn[col] + 3) >> 2;
        const float4* v4 = (const float4*)(wvals + (size_t)col * 256);
        const ushort4* i4 = (const ushort4*)(widx + (size_t)col * 256);
        const float* xr = xs[wv];
        float p = 0.0f;
        #pragma unroll 2
        for (int i = 0; i < n4; ++i) {
            float4 vv = v4[i];
            ushort4 ii = i4[i];
            p = __fmaf_rn(xr[ii.x], vv.x, p);
            p = __fmaf_rn(xr[ii.y], vv.y, p);
            p = __fmaf_rn(xr[ii.z], vv.z, p);
            p = __fmaf_rn(xr[ii.w], vv.w, p);
        }
        rnp[row * 64 + lane] = p;
    }
}

// ---------------------------------------------------------------- kernel C2'
__global__ __launch_bounds__(256)
void k_sel2_full(const float* __restrict__ x, const float* __restrict__ w,
                 const int2* __restrict__ cnt, const int* __restrict__ rcol,
                 float* __restrict__ rnp, const int* __restrict__ flag) {
    __shared__ float xs[4][IN_DIM];
    const int tid = threadIdx.x;
    const int lane = tid & 63;
    const int wv = tid >> 6;
    const int row = blockIdx.x * 4 + wv;
    const bool bipolar = (*flag == 0);

    const float4* xr4 = (const float4*)(x + (size_t)row * IN_DIM);
    #pragma unroll
    for (int u = 0; u < 4; ++u) {
        float4 xv = xr4[lane + 64 * u];
        if (bipolar) {
            xv.x = __fmul_rn(__fadd_rn(xv.x, -0.5f), 2.0f);
            xv.y = __fmul_rn(__fadd_rn(xv.y, -0.5f), 2.0f);
            xv.z = __fmul_rn(__fadd_rn(xv.z, -0.5f), 2.0f);
            xv.w = __fmul_rn(__fadd_rn(xv.w, -0.5f), 2.0f);
        }
        ((float4*)xs[wv])[lane + 64 * u] = xv;
    }
    __syncthreads();

    int nb = cnt[row].x; if (nb > 64) nb = 64;
    if (lane < nb) {
        const int col = rcol[row * 64 + lane];
        const float4* wr4 = (const float4*)(w + (size_t)col * IN_DIM);
        const float4* xs4 = (const float4*)xs[wv];
        float p = 0.0f;
        #pragma unroll 4
        for (int i = 0; i < IN_DIM / 4; ++i) {
            float4 xv = xs4[i];
            float4 wvv = wr4[i];
            p = __fmaf_rn(xv.x, wvv.x, p);
            p = __fmaf_rn(xv.y, wvv.y, p);
            p = __fmaf_rn(xv.z, wvv.z, p);
            p = __fmaf_rn(xv.w, wvv.w, p);
        }
        rnp[row * 64 + lane] = p;
    }
}

// ---------------------------------------------------------------- kernel C3
// per row: rank records, encode from f16 fast values, L2 norm, write f32.
// f16 reads complete before the norm barrier; f32 writes after => safe
// in-place overwrite of the packed f16 region.
__global__ __launch_bounds__(256)
void k_sel3(float* __restrict__ po, const float2* __restrict__ thr,
            const int2* __restrict__ cnt, const int* __restrict__ rcol,
            const float* __restrict__ rnp) {
    __shared__ int bcol[64];
    __shared__ float bnp[64];
    __shared__ unsigned char bsel[64];
    __shared__ float fred[4];
    const int row = blockIdx.x;
    const int tid = threadIdx.x;
    const int lane = tid & 63, wq = tid >> 6;
    const float2 th = thr[row];
    const int2 cn = cnt[row];
    const float thi = th.x, tlo = th.y;
    const int nb = cn.x, krem = cn.y;
    const int nbc = nb > 64 ? 64 : nb;
    const bool need = (nb != krem);

    const _Float16* fr = (const _Float16*)((const char*)po + (size_t)row * OUT_DIM * 4);
    half8 h0 = *(const half8*)&fr[tid * 8];
    half8 h1 = *(const half8*)&fr[2048 + tid * 8];

    if (tid < nbc) { bcol[tid] = rcol[row * 64 + tid]; bnp[tid] = rnp[row * 64 + tid]; }
    __syncthreads();
    if (tid < nbc) {
        const float v = bnp[tid];
        int gc = 0;
        for (int l = 0; l < nbc; ++l) gc += (bnp[l] > v);
        bsel[tid] = (gc < krem) ? 1 : 0;
    }
    __syncthreads();

    float ov[16];
    float nrm2 = 0.0f;
    #pragma unroll
    for (int e = 0; e < 16; ++e) {
        float f = (e < 8) ? (float)h0[e] : (float)h1[e - 8];
        const int j = (e < 8) ? (tid * 8 + e) : (2048 + tid * 8 + e - 8);
        bool sel = (f > thi);
        float val = f;
        if (!sel && f >= tlo) {
            if (!need) sel = true;
            else {
                for (int m = 0; m < nbc; ++m)
                    if (bcol[m] == j) {
                        sel = (bsel[m] != 0);
                        val = bnp[m];
                        break;
                    }
            }
        }
        float eo = (sel && val > 0.0f) ? val : 0.0f;
        ov[e] = eo;
        nrm2 += eo * eo;
    }
    #pragma unroll
    for (int off = 32; off > 0; off >>= 1)
        nrm2 += __shfl_xor(nrm2, off);
    if (lane == 0) fred[wq] = nrm2;
    __syncthreads();
    const float total = fred[0] + fred[1] + fred[2] + fred[3];
    const float inv = 1.0f / fmaxf(sqrtf(total), 1e-12f);

    float4* p4 = (float4*)(po + (size_t)row * OUT_DIM);
    #pragma unroll
    for (int h = 0; h < 2; ++h) {
        const int base = (h == 0) ? 0 : 8;
        const int fi = (h == 0) ? (tid * 2) : (512 + tid * 2);
        float4 o0 = make_float4(ov[base + 0] * inv, ov[base + 1] * inv,
                                ov[base + 2] * inv, ov[base + 3] * inv);
        float4 o1 = make_float4(ov[base + 4] * inv, ov[base + 5] * inv,
                                ov[base + 6] * inv, ov[base + 7] * inv);
        p4[fi] = o0;
        p4[fi + 1] = o1;
    }
}

// ---------------------------------------------------------------- launch
extern "C" void kernel_launch(void* const* d_in, const int* in_sizes, int n_in,
                              void* d_out, int out_size, void* d_ws, size_t ws_size,
                              hipStream_t stream) {
    const float* x = (const float*)d_in[0];
    const float* w = (const float*)d_in[1];
    float* out = (float*)d_out;
    int* flag = (int*)d_ws;

    hipMemsetAsync(flag, 0, sizeof(int), stream);
    k_hasneg<<<2048, 256, 0, stream>>>(x, BATCH * IN_DIM, flag);

    dim3 g(BATCH / 128, OUT_DIM / 128);
    _Float16* xh = (_Float16*)((char*)d_ws + WS_XH_OFF);
    _Float16* wh = (_Float16*)((char*)d_ws + WS_WH_OFF);
    k_cvt<<<2048, 256, 0, stream>>>(x, w, xh, wh, flag);
    k_gemm16<<<g, 256, 0, stream>>>(xh, wh, out);

    float2* thr = (float2*)((char*)d_ws + WS_THR_OFF);
    int2*   cnt = (int2*)((char*)d_ws + WS_CNT_OFF);
    int*    rcol = (int*)((char*)d_ws + WS_COL_OFF);
    float*  rnp = (float*)((char*)d_ws + WS_NP_OFF);
    k_sel1<<<BATCH, 256, 0, stream>>>(out, thr, cnt, rcol);
    if (ws_size >= WS_NEED3) {
        float* wv = (float*)((char*)d_ws + WS_WV_OFF);
        unsigned short* wi = (unsigned short*)((char*)d_ws + WS_WI_OFF);
        int* wn = (int*)((char*)d_ws + WS_WN_OFF);
        k_wcomp<<<OUT_DIM / 4, 256, 0, stream>>>(w, wv, wi, wn);
        k_sel2<<<BATCH / 4, 256, 0, stream>>>(x, wv, wi, wn, cnt, rcol, rnp, flag);
    } else {
        k_sel2_full<<<BATCH / 4, 256, 0, stream>>>(x, w, cnt, rcol, rnp, flag);
    }
    k_sel3<<<BATCH, 256, 0, stream>>>(out, thr, cnt, rcol, rnp);
}

// Round 24
// 450.861 us; speedup vs baseline: 1.8916x; 1.0217x over previous
//
#include <hip/hip_runtime.h>

#define BATCH   16384
#define IN_DIM  1024
#define OUT_DIM 4096
#define K_TOP   409
#define DELTA_W 6.5e-3f

typedef _Float16 half8  __attribute__((ext_vector_type(8)));
typedef _Float16 half4v __attribute__((ext_vector_type(4)));
typedef float    f32x4  __attribute__((ext_vector_type(4)));

// workspace layout
#define WS_XH_OFF   256
#define WS_WH_OFF   (WS_XH_OFF + (size_t)BATCH * IN_DIM * 2)
#define WS_THR_OFF  (WS_WH_OFF + (size_t)OUT_DIM * IN_DIM * 2)
#define WS_CNT_OFF  (WS_THR_OFF + (size_t)BATCH * 8)
#define WS_COL_OFF  (WS_CNT_OFF + (size_t)BATCH * 8)
#define WS_NP_OFF   (WS_COL_OFF + (size_t)BATCH * 64 * 4)
#define WS_WV_OFF   (WS_NP_OFF + (size_t)BATCH * 64 * 4)
#define WS_WI_OFF   (WS_WV_OFF + (size_t)OUT_DIM * 256 * 4)
#define WS_WN_OFF   (WS_WI_OFF + (size_t)OUT_DIM * 256 * 2)
#define WS_NEEDED   (WS_WH_OFF + (size_t)OUT_DIM * IN_DIM * 2)
#define WS_NEED3    (WS_WN_OFF + (size_t)OUT_DIM * 4)

// fast values stored as f16 packed in the FIRST 8KB of each row's 16KB slot.

// ---------------------------------------------------------------- kernel A
__global__ __launch_bounds__(256)
void k_hasneg(const float* __restrict__ x, int n, int* __restrict__ flag) {
    const int stride = gridDim.x * blockDim.x;
    bool neg = false;
    for (int i = blockIdx.x * blockDim.x + threadIdx.x; i < n; i += stride)
        neg |= (x[i] < 0.0f);
    unsigned long long b = __ballot(neg);
    if (b != 0ULL && (threadIdx.x & 63) == 0)
        atomicOr(flag, 1);
}

// ---------------------------------------------------------------- kernel A2
__global__ __launch_bounds__(256)
void k_cvt(const float* __restrict__ x, const float* __restrict__ w,
           _Float16* __restrict__ xh, _Float16* __restrict__ wh,
           const int* __restrict__ flag) {
    const bool bipolar = (*flag == 0);
    const int stride = gridDim.x * blockDim.x;
    const int nx4 = BATCH * IN_DIM / 4;
    const int nw4 = OUT_DIM * IN_DIM / 4;
    for (int i = blockIdx.x * blockDim.x + threadIdx.x; i < nx4; i += stride) {
        float4 v = ((const float4*)x)[i];
        if (bipolar) {
            v.x = (v.x - 0.5f) * 2.0f; v.y = (v.y - 0.5f) * 2.0f;
            v.z = (v.z - 0.5f) * 2.0f; v.w = (v.w - 0.5f) * 2.0f;
        }
        ((half4v*)xh)[i] = half4v{ (_Float16)v.x, (_Float16)v.y,
                                   (_Float16)v.z, (_Float16)v.w };
    }
    for (int i = blockIdx.x * blockDim.x + threadIdx.x; i < nw4; i += stride) {
        float4 u = ((const float4*)w)[i];
        ((half4v*)wh)[i] = half4v{ (_Float16)u.x, (_Float16)u.y,
                                   (_Float16)u.z, (_Float16)u.w };
    }
}

// ---------------------------------------------------------------- kernel A3
__global__ __launch_bounds__(256)
void k_wcomp(const float* __restrict__ w, float* __restrict__ wv,
             unsigned short* __restrict__ wi, int* __restrict__ wn) {
    const int lane = threadIdx.x & 63;
    const int row = blockIdx.x * 4 + (threadIdx.x >> 6);
    const float* wr = w + (size_t)row * IN_DIM;
    const float4* wr4 = (const float4*)(wr + lane * 16);
    float4 v[4];
    int cnt = 0;
    #pragma unroll
    for (int q = 0; q < 4; ++q) {
        v[q] = wr4[q];
        cnt += (v[q].x != 0.0f) + (v[q].y != 0.0f)
             + (v[q].z != 0.0f) + (v[q].w != 0.0f);
    }
    int off = cnt;
    #pragma unroll
    for (int d = 1; d < 64; d <<= 1) {
        int t = __shfl_up(off, d);
        if (lane >= d) off += t;
    }
    const int total = __shfl(off, 63);
    off -= cnt;
    float* dv = wv + (size_t)row * 256;
    unsigned short* di = wi + (size_t)row * 256;
    int pos = off;
    #pragma unroll
    for (int q = 0; q < 4; ++q) {
        #pragma unroll
        for (int e = 0; e < 4; ++e) {
            float f = (e == 0) ? v[q].x : (e == 1) ? v[q].y
                    : (e == 2) ? v[q].z : v[q].w;
            if (f != 0.0f) {
                dv[pos] = f;
                di[pos] = (unsigned short)(lane * 16 + q * 4 + e);
                ++pos;
            }
        }
    }
    if (lane == 0) {
        const int n4 = (total + 3) & ~3;
        for (int i = total; i < n4 && i < 256; ++i) { dv[i] = 0.0f; di[i] = 0; }
        wn[row] = total;
    }
}

// ---------------------------------------------------------------- kernel B
// 256x256 tile, 512 threads (8 waves 2x4, each wave 128x64), BK=64,
// double-buffered LDS (128 KB), one barrier per K-step (prefetch overlap).
// Staging/swizzle relation identical to the r16-proven kernel (0 conflicts):
// pre-swizzled global source slot (lane&7)^(lane>>3), linear LDS dest,
// XOR'd fragment ds_read_b128. 64 MFMA : 24 ds_read per wave per K-step.
// Output: f16 fast values packed into each row's f32 slot.
__global__ __launch_bounds__(512, 2)
void k_gemm16(const _Float16* __restrict__ xh, const _Float16* __restrict__ wh,
              float* __restrict__ out) {
    __shared__ _Float16 Ah[2][256 * 64];
    __shared__ _Float16 Bh[2][256 * 64];
    const int tid = threadIdx.x;
    const int bm = blockIdx.x, bn = blockIdx.y;
    const int lane = tid & 63;
    const int wv = tid >> 6;                 // 0..7
    const int wm = wv >> 2, wn = wv & 3;     // 2 x 4 wave grid
    const int lr = lane & 15, lk = lane >> 4;

    const int srow = (lane >> 3);            // 0..7 within 8-row issue
    const int sslot = (lane & 7) ^ srow;     // pre-swizzled source slot
    f32x4 acc[8][4] = {};

    const _Float16* aS[4]; const _Float16* bS[4];
    int dOff[4];
    #pragma unroll
    for (int i = 0; i < 4; ++i) {
        const int rb = i * 64 + wv * 8;      // 8 waves x 4 issues cover 256 rows
        aS[i] = xh + (size_t)(bm * 256 + rb + srow) * IN_DIM + sslot * 8;
        bS[i] = wh + (size_t)(bn * 256 + rb + srow) * IN_DIM + sslot * 8;
        dOff[i] = rb * 64;
    }

    // prologue: stage tile 0 into buf 0
    #pragma unroll
    for (int i = 0; i < 4; ++i) {
        __builtin_amdgcn_global_load_lds((const __attribute__((address_space(1))) void*)(aS[i]), (__attribute__((address_space(3))) void*)&Ah[0][dOff[i]], 16, 0, 0);
        __builtin_amdgcn_global_load_lds((const __attribute__((address_space(1))) void*)(bS[i]), (__attribute__((address_space(3))) void*)&Bh[0][dOff[i]], 16, 0, 0);
    }
    __syncthreads();

    int cur = 0;
    #pragma unroll 1
    for (int t = 0; t < 16; ++t) {
        if (t < 15) {                        // prefetch next tile into buf^1
            const int kt = (t + 1) * 64;
            #pragma unroll
            for (int i = 0; i < 4; ++i) {
                __builtin_amdgcn_global_load_lds((const __attribute__((address_space(1))) void*)(aS[i] + kt), (__attribute__((address_space(3))) void*)&Ah[cur ^ 1][dOff[i]], 16, 0, 0);
                __builtin_amdgcn_global_load_lds((const __attribute__((address_space(1))) void*)(bS[i] + kt), (__attribute__((address_space(3))) void*)&Bh[cur ^ 1][dOff[i]], 16, 0, 0);
            }
        }
        #pragma unroll
        for (int h = 0; h < 2; ++h) {
            half8 bf[4];
            #pragma unroll
            for (int j = 0; j < 4; ++j) {
                const int rbv = wn * 64 + j * 16 + lr;
                const int sb = (h * 4 + lk) ^ (rbv & 7);
                bf[j] = *(const half8*)&Bh[cur][rbv * 64 + (sb << 3)];
            }
            #pragma unroll
            for (int hf = 0; hf < 2; ++hf) {
                half8 af[4];
                #pragma unroll
                for (int i = 0; i < 4; ++i) {
                    const int ra = wm * 128 + (hf * 4 + i) * 16 + lr;
                    const int sa = (h * 4 + lk) ^ (ra & 7);
                    af[i] = *(const half8*)&Ah[cur][ra * 64 + (sa << 3)];
                }
                #pragma unroll
                for (int i = 0; i < 4; ++i)
                    #pragma unroll
                    for (int j = 0; j < 4; ++j)
                        acc[hf * 4 + i][j] = __builtin_amdgcn_mfma_f32_16x16x32_f16(
                            af[i], bf[j], acc[hf * 4 + i][j], 0, 0, 0);
            }
        }
        __syncthreads();                     // drains prefetch + ends reads
        cur ^= 1;
    }
    // epilogue: f16 store into each row's packed region
    #pragma unroll
    for (int i = 0; i < 8; ++i)
        #pragma unroll
        for (int j = 0; j < 4; ++j)
            #pragma unroll
            for (int q = 0; q < 4; ++q) {
                const int row = bm * 256 + wm * 128 + i * 16 + lk * 4 + q;
                const int col = bn * 256 + wn * 64 + j * 16 + lr;
                _Float16* fo = (_Float16*)((char*)out + (size_t)row * OUT_DIM * 4);
                fo[col] = (_Float16)acc[i][j][q];
            }
}

// ---------------------------------------------------------------- kernel C1
__global__ __launch_bounds__(256)
void k_sel1(const float* __restrict__ po, float2* __restrict__ thr,
            int2* __restrict__ cnt, int* __restrict__ rcol) {
    __shared__ unsigned int bins[256];
    __shared__ float fred[4];
    __shared__ unsigned int wsum[4];
    __shared__ int s_b, s_b2;
    __shared__ unsigned int s_hi, s_slot, s_hi1;
    const int row = blockIdx.x;
    const int tid = threadIdx.x;
    const int lane = tid & 63, wq = tid >> 6;
    const _Float16* fr = (const _Float16*)((const char*)po + (size_t)row * OUT_DIM * 4);

    half8 h0 = *(const half8*)&fr[tid * 8];
    half8 h1 = *(const half8*)&fr[2048 + tid * 8];
    float fv[16];
    float vmax = -1e30f;
    #pragma unroll
    for (int e = 0; e < 8; ++e) {
        fv[e] = (float)h0[e];
        fv[8 + e] = (float)h1[e];
        vmax = fmaxf(vmax, fmaxf(fv[e], fv[8 + e]));
    }
    #pragma unroll
    for (int off = 32; off > 0; off >>= 1)
        vmax = fmaxf(vmax, __shfl_xor(vmax, off));
    if (lane == 0) fred[wq] = vmax;
    bins[tid] = 0;
    if (tid == 0) { s_hi = 0; s_slot = 0; s_b = 0; s_b2 = 0; s_hi1 = 0; }
    __syncthreads();
    vmax = fmaxf(fmaxf(fmaxf(fred[0], fred[1]), fmaxf(fred[2], fred[3])), 1e-6f);
    const float scale1 = 256.0f / vmax;
    const float invscale1 = vmax * (1.0f / 256.0f);

    #pragma unroll
    for (int e = 0; e < 16; ++e) {
        float f = fv[e];
        if (f > 0.0f) {
            int b = (int)(f * scale1);
            if (b > 255) b = 255;
            atomicAdd(&bins[b], 1u);
        }
    }
    __syncthreads();
    {
        const unsigned int c = bins[255 - tid];
        unsigned int sc = c;
        #pragma unroll
        for (int off = 1; off < 64; off <<= 1) {
            unsigned int t2 = __shfl_up(sc, off);
            if (lane >= off) sc += t2;
        }
        if (lane == 63) wsum[wq] = sc;
        __syncthreads();
        for (int q = 0; q < wq; ++q) sc += wsum[q];
        if ((int)sc >= K_TOP && (int)(sc - c) < K_TOP) {
            s_b = 255 - tid;
            s_hi1 = sc - c;
        }
    }
    __syncthreads();
    const int b1 = s_b;
    const unsigned int hi1 = s_hi1;
    const float blo = (float)b1 * invscale1;
    const float scale2 = scale1 * 256.0f;
    const float s2w = invscale1 * (1.0f / 256.0f);

    bins[tid] = 0;
    __syncthreads();
    #pragma unroll
    for (int e = 0; e < 16; ++e) {
        float f = fv[e];
        if (f > 0.0f) {
            int b = (int)(f * scale1);
            if (b > 255) b = 255;
            if (b == b1) {
                int b2 = (int)((f - blo) * scale2);
                if (b2 < 0) b2 = 0;
                if (b2 > 255) b2 = 255;
                atomicAdd(&bins[b2], 1u);
            }
        }
    }
    __syncthreads();
    {
        const unsigned int c = bins[255 - tid];
        unsigned int sc = c;
        #pragma unroll
        for (int off = 1; off < 64; off <<= 1) {
            unsigned int t2 = __shfl_up(sc, off);
            if (lane >= off) sc += t2;
        }
        if (lane == 63) wsum[wq] = sc;
        __syncthreads();
        for (int q = 0; q < wq; ++q) sc += wsum[q];
        if ((int)(hi1 + sc) >= K_TOP && (int)(hi1 + sc - c) < K_TOP)
            s_b2 = 255 - tid;
    }
    __syncthreads();
    const float thi = blo + (float)(s_b2 + 1) * s2w + DELTA_W;
    const float tlo = blo + (float)s_b2 * s2w - DELTA_W;

    #pragma unroll
    for (int e = 0; e < 16; ++e) {
        float f = fv[e];
        if (f > thi) atomicAdd(&s_hi, 1u);
        else if (f >= tlo) {
            unsigned int p = atomicAdd(&s_slot, 1u);
            const int j = (e < 8) ? (tid * 8 + e) : (2048 + tid * 8 + e - 8);
            if (p < 64) rcol[row * 64 + p] = j;
        }
    }
    __syncthreads();
    if (tid == 0) {
        int nb = (int)s_slot;
        int krem = K_TOP - (int)s_hi;
        if (krem > nb) krem = nb;
        if (krem < 0) krem = 0;
        thr[row] = make_float2(thi, tlo);
        cnt[row] = make_int2(nb, krem);
    }
}

// ---------------------------------------------------------------- kernel C2
__global__ __launch_bounds__(256)
void k_sel2(const float* __restrict__ x, const float* __restrict__ wvals,
            const unsigned short* __restrict__ widx, const int* __restrict__ wn,
            const int2* __restrict__ cnt, const int* __restrict__ rcol,
            float* __restrict__ rnp, const int* __restrict__ flag) {
    __shared__ float xs[4][IN_DIM];
    const int tid = threadIdx.x;
    const int lane = tid & 63;
    const int wv = tid >> 6;
    const int row = blockIdx.x * 4 + wv;
    const bool bipolar = (*flag == 0);

    const float4* xr4 = (const float4*)(x + (size_t)row * IN_DIM);
    #pragma unroll
    for (int u = 0; u < 4; ++u) {
        float4 xv = xr4[lane + 64 * u];
        if (bipolar) {
            xv.x = __fmul_rn(__fadd_rn(xv.x, -0.5f), 2.0f);
            xv.y = __fmul_rn(__fadd_rn(xv.y, -0.5f), 2.0f);
            xv.z = __fmul_rn(__fadd_rn(xv.z, -0.5f), 2.0f);
            xv.w = __fmul_rn(__fadd_rn(xv.w, -0.5f), 2.0f);
        }
        ((float4*)xs[wv])[lane + 64 * u] = xv;
    }
    __syncthreads();

    int nb = cnt[row].x; if (nb > 64) nb = 64;
    if (lane < nb) {
        const int col = rcol[row * 64 + lane];
        const int n4 = (wn[col] + 3) >> 2;
        const float4* v4 = (const float4*)(wvals + (size_t)col * 256);
        const ushort4* i4 = (const ushort4*)(widx + (size_t)col * 256);
        const float* xr = xs[wv];
        float p = 0.0f;
        #pragma unroll 2
        for (int i = 0; i < n4; ++i) {
            float4 vv = v4[i];
            ushort4 ii = i4[i];
            p = __fmaf_rn(xr[ii.x], vv.x, p);
            p = __fmaf_rn(xr[ii.y], vv.y, p);
            p = __fmaf_rn(xr[ii.z], vv.z, p);
            p = __fmaf_rn(xr[ii.w], vv.w, p);
        }
        rnp[row * 64 + lane] = p;
    }
}

// ---------------------------------------------------------------- kernel C2'
__global__ __launch_bounds__(256)
void k_sel2_full(const float* __restrict__ x, const float* __restrict__ w,
                 const int2* __restrict__ cnt, const int* __restrict__ rcol,
                 float* __restrict__ rnp, const int* __restrict__ flag) {
    __shared__ float xs[4][IN_DIM];
    const int tid = threadIdx.x;
    const int lane = tid & 63;
    const int wv = tid >> 6;
    const int row = blockIdx.x * 4 + wv;
    const bool bipolar = (*flag == 0);

    const float4* xr4 = (const float4*)(x + (size_t)row * IN_DIM);
    #pragma unroll
    for (int u = 0; u < 4; ++u) {
        float4 xv = xr4[lane + 64 * u];
        if (bipolar) {
            xv.x = __fmul_rn(__fadd_rn(xv.x, -0.5f), 2.0f);
            xv.y = __fmul_rn(__fadd_rn(xv.y, -0.5f), 2.0f);
            xv.z = __fmul_rn(__fadd_rn(xv.z, -0.5f), 2.0f);
            xv.w = __fmul_rn(__fadd_rn(xv.w, -0.5f), 2.0f);
        }
        ((float4*)xs[wv])[lane + 64 * u] = xv;
    }
    __syncthreads();

    int nb = cnt[row].x; if (nb > 64) nb = 64;
    if (lane < nb) {
        const int col = rcol[row * 64 + lane];
        const float4* wr4 = (const float4*)(w + (size_t)col * IN_DIM);
        const float4* xs4 = (const float4*)xs[wv];
        float p = 0.0f;
        #pragma unroll 4
        for (int i = 0; i < IN_DIM / 4; ++i) {
            float4 xv = xs4[i];
            float4 wvv = wr4[i];
            p = __fmaf_rn(xv.x, wvv.x, p);
            p = __fmaf_rn(xv.y, wvv.y, p);
            p = __fmaf_rn(xv.z, wvv.z, p);
            p = __fmaf_rn(xv.w, wvv.w, p);
        }
        rnp[row * 64 + lane] = p;
    }
}

// ---------------------------------------------------------------- kernel C3
__global__ __launch_bounds__(256)
void k_sel3(float* __restrict__ po, const float2* __restrict__ thr,
            const int2* __restrict__ cnt, const int* __restrict__ rcol,
            const float* __restrict__ rnp) {
    __shared__ int bcol[64];
    __shared__ float bnp[64];
    __shared__ unsigned char bsel[64];
    __shared__ float fred[4];
    const int row = blockIdx.x;
    const int tid = threadIdx.x;
    const int lane = tid & 63, wq = tid >> 6;
    const float2 th = thr[row];
    const int2 cn = cnt[row];
    const float thi = th.x, tlo = th.y;
    const int nb = cn.x, krem = cn.y;
    const int nbc = nb > 64 ? 64 : nb;
    const bool need = (nb != krem);

    const _Float16* fr = (const _Float16*)((const char*)po + (size_t)row * OUT_DIM * 4);
    half8 h0 = *(const half8*)&fr[tid * 8];
    half8 h1 = *(const half8*)&fr[2048 + tid * 8];

    if (tid < nbc) { bcol[tid] = rcol[row * 64 + tid]; bnp[tid] = rnp[row * 64 + tid]; }
    __syncthreads();
    if (tid < nbc) {
        const float v = bnp[tid];
        int gc = 0;
        for (int l = 0; l < nbc; ++l) gc += (bnp[l] > v);
        bsel[tid] = (gc < krem) ? 1 : 0;
    }
    __syncthreads();

    float ov[16];
    float nrm2 = 0.0f;
    #pragma unroll
    for (int e = 0; e < 16; ++e) {
        float f = (e < 8) ? (float)h0[e] : (float)h1[e - 8];
        const int j = (e < 8) ? (tid * 8 + e) : (2048 + tid * 8 + e - 8);
        bool sel = (f > thi);
        float val = f;
        if (!sel && f >= tlo) {
            if (!need) sel = true;
            else {
                for (int m = 0; m < nbc; ++m)
                    if (bcol[m] == j) {
                        sel = (bsel[m] != 0);
                        val = bnp[m];
                        break;
                    }
            }
        }
        float eo = (sel && val > 0.0f) ? val : 0.0f;
        ov[e] = eo;
        nrm2 += eo * eo;
    }
    #pragma unroll
    for (int off = 32; off > 0; off >>= 1)
        nrm2 += __shfl_xor(nrm2, off);
    if (lane == 0) fred[wq] = nrm2;
    __syncthreads();
    const float total = fred[0] + fred[1] + fred[2] + fred[3];
    const float inv = 1.0f / fmaxf(sqrtf(total), 1e-12f);

    float4* p4 = (float4*)(po + (size_t)row * OUT_DIM);
    #pragma unroll
    for (int h = 0; h < 2; ++h) {
        const int base = (h == 0) ? 0 : 8;
        const int fi = (h == 0) ? (tid * 2) : (512 + tid * 2);
        float4 o0 = make_float4(ov[base + 0] * inv, ov[base + 1] * inv,
                                ov[base + 2] * inv, ov[base + 3] * inv);
        float4 o1 = make_float4(ov[base + 4] * inv, ov[base + 5] * inv,
                                ov[base + 6] * inv, ov[base + 7] * inv);
        p4[fi] = o0;
        p4[fi + 1] = o1;
    }
}

// ---------------------------------------------------------------- launch
extern "C" void kernel_launch(void* const* d_in, const int* in_sizes, int n_in,
                              void* d_out, int out_size, void* d_ws, size_t ws_size,
                              hipStream_t stream) {
    const float* x = (const float*)d_in[0];
    const float* w = (const float*)d_in[1];
    float* out = (float*)d_out;
    int* flag = (int*)d_ws;

    hipMemsetAsync(flag, 0, sizeof(int), stream);
    k_hasneg<<<2048, 256, 0, stream>>>(x, BATCH * IN_DIM, flag);

    dim3 g(BATCH / 256, OUT_DIM / 256);
    _Float16* xh = (_Float16*)((char*)d_ws + WS_XH_OFF);
    _Float16* wh = (_Float16*)((char*)d_ws + WS_WH_OFF);
    k_cvt<<<2048, 256, 0, stream>>>(x, w, xh, wh, flag);
    k_gemm16<<<g, 512, 0, stream>>>(xh, wh, out);

    float2* thr = (float2*)((char*)d_ws + WS_THR_OFF);
    int2*   cnt = (int2*)((char*)d_ws + WS_CNT_OFF);
    int*    rcol = (int*)((char*)d_ws + WS_COL_OFF);
    float*  rnp = (float*)((char*)d_ws + WS_NP_OFF);
    k_sel1<<<BATCH, 256, 0, stream>>>(out, thr, cnt, rcol);
    if (ws_size >= WS_NEED3) {
        float* wv = (float*)((char*)d_ws + WS_WV_OFF);
        unsigned short* wi = (unsigned short*)((char*)d_ws + WS_WI_OFF);
        int* wn = (int*)((char*)d_ws + WS_WN_OFF);
        k_wcomp<<<OUT_DIM / 4, 256, 0, stream>>>(w, wv, wi, wn);
        k_sel2<<<BATCH / 4, 256, 0, stream>>>(x, wv, wi, wn, cnt, rcol, rnp, flag);
    } else {
        k_sel2_full<<<BATCH / 4, 256, 0, stream>>>(x, w, cnt, rcol, rnp, flag);
    }
    k_sel3<<<BATCH, 256, 0, stream>>>(out, thr, cnt, rcol, rnp);
}

// Round 25
// 438.267 us; speedup vs baseline: 1.9459x; 1.0287x over previous
//
#include <hip/hip_runtime.h>

#define BATCH   16384
#define IN_DIM  1024
#define OUT_DIM 4096
#define K_TOP   409
#define DELTA_W 6.5e-3f

typedef _Float16 half8  __attribute__((ext_vector_type(8)));
typedef _Float16 half4v __attribute__((ext_vector_type(4)));
typedef float    f32x4  __attribute__((ext_vector_type(4)));

// workspace layout
#define WS_XH_OFF   256
#define WS_WH_OFF   (WS_XH_OFF + (size_t)BATCH * IN_DIM * 2)
#define WS_WV_OFF   (WS_WH_OFF + (size_t)OUT_DIM * IN_DIM * 2)
#define WS_WI_OFF   (WS_WV_OFF + (size_t)OUT_DIM * 256 * 4)
#define WS_WN_OFF   (WS_WI_OFF + (size_t)OUT_DIM * 256 * 2)
#define WS_NEEDED   (WS_WV_OFF)
#define WS_NEED3    (WS_WN_OFF + (size_t)OUT_DIM * 4)

// fast values stored as f16 packed in the FIRST 8KB of each row's 16KB slot.

// ---------------------------------------------------------------- kernel A
__global__ __launch_bounds__(256)
void k_hasneg(const float* __restrict__ x, int n, int* __restrict__ flag) {
    const int stride = gridDim.x * blockDim.x;
    bool neg = false;
    for (int i = blockIdx.x * blockDim.x + threadIdx.x; i < n; i += stride)
        neg |= (x[i] < 0.0f);
    unsigned long long b = __ballot(neg);
    if (b != 0ULL && (threadIdx.x & 63) == 0)
        atomicOr(flag, 1);
}

// ---------------------------------------------------------------- kernel A2
// fused convert + CSR: each block (4 waves) handles 4 w-rows (f16 convert +
// CSR compression, sharing one read) and a 16-row slice of x (bipolar+f16).
__global__ __launch_bounds__(256)
void k_cvt2(const float* __restrict__ x, const float* __restrict__ w,
            _Float16* __restrict__ xh, _Float16* __restrict__ wh,
            float* __restrict__ wv, unsigned short* __restrict__ wi,
            int* __restrict__ wn, int use_csr, const int* __restrict__ flag) {
    const bool bipolar = (*flag == 0);
    const int tid = threadIdx.x;
    const int lane = tid & 63;
    const int wrow = blockIdx.x * 4 + (tid >> 6);

    // ---- w: convert + CSR (wave per row; lane owns cols [lane*16,+16))
    const float* wr = w + (size_t)wrow * IN_DIM;
    const float4* wr4 = (const float4*)(wr + lane * 16);
    _Float16* whr = wh + (size_t)wrow * IN_DIM + lane * 16;
    float4 v[4];
    int cnt = 0;
    #pragma unroll
    for (int q = 0; q < 4; ++q) {
        v[q] = wr4[q];
        ((half4v*)whr)[q] = half4v{ (_Float16)v[q].x, (_Float16)v[q].y,
                                    (_Float16)v[q].z, (_Float16)v[q].w };
        cnt += (v[q].x != 0.0f) + (v[q].y != 0.0f)
             + (v[q].z != 0.0f) + (v[q].w != 0.0f);
    }
    if (use_csr) {
        int off = cnt;
        #pragma unroll
        for (int d = 1; d < 64; d <<= 1) {
            int t = __shfl_up(off, d);
            if (lane >= d) off += t;
        }
        const int total = __shfl(off, 63);
        off -= cnt;
        float* dv = wv + (size_t)wrow * 256;
        unsigned short* di = wi + (size_t)wrow * 256;
        int pos = off;
        #pragma unroll
        for (int q = 0; q < 4; ++q) {
            #pragma unroll
            for (int e = 0; e < 4; ++e) {
                float f = (e == 0) ? v[q].x : (e == 1) ? v[q].y
                        : (e == 2) ? v[q].z : v[q].w;
                if (f != 0.0f) {
                    dv[pos] = f;
                    di[pos] = (unsigned short)(lane * 16 + q * 4 + e);
                    ++pos;
                }
            }
        }
        if (lane == 0) {
            const int n4 = (total + 3) & ~3;
            for (int i = total; i < n4 && i < 256; ++i) { dv[i] = 0.0f; di[i] = 0; }
            wn[wrow] = total;
        }
    }

    // ---- x slice: 16 rows per block = 4096 float4, 16 per thread
    const float4* x4 = (const float4*)x;
    half4v* xh4 = (half4v*)xh;
    const int base = blockIdx.x * 4096;
    #pragma unroll
    for (int u = 0; u < 16; ++u) {
        const int idx = base + u * 256 + tid;
        float4 xv = x4[idx];
        if (bipolar) {
            xv.x = (xv.x - 0.5f) * 2.0f; xv.y = (xv.y - 0.5f) * 2.0f;
            xv.z = (xv.z - 0.5f) * 2.0f; xv.w = (xv.w - 0.5f) * 2.0f;
        }
        xh4[idx] = half4v{ (_Float16)xv.x, (_Float16)xv.y,
                           (_Float16)xv.z, (_Float16)xv.w };
    }
}

// ---------------------------------------------------------------- kernel B
// (r24: 256x256 tile, 8 waves, BK=64, double-buffered LDS, one barrier per
// K-step; r16-proven pre-swizzled global_load_lds + XOR fragment reads.)
__global__ __launch_bounds__(512, 2)
void k_gemm16(const _Float16* __restrict__ xh, const _Float16* __restrict__ wh,
              float* __restrict__ out) {
    __shared__ _Float16 Ah[2][256 * 64];
    __shared__ _Float16 Bh[2][256 * 64];
    const int tid = threadIdx.x;
    const int bm = blockIdx.x, bn = blockIdx.y;
    const int lane = tid & 63;
    const int wv = tid >> 6;                 // 0..7
    const int wm = wv >> 2, wn = wv & 3;     // 2 x 4 wave grid
    const int lr = lane & 15, lk = lane >> 4;

    const int srow = (lane >> 3);
    const int sslot = (lane & 7) ^ srow;
    f32x4 acc[8][4] = {};

    const _Float16* aS[4]; const _Float16* bS[4];
    int dOff[4];
    #pragma unroll
    for (int i = 0; i < 4; ++i) {
        const int rb = i * 64 + wv * 8;
        aS[i] = xh + (size_t)(bm * 256 + rb + srow) * IN_DIM + sslot * 8;
        bS[i] = wh + (size_t)(bn * 256 + rb + srow) * IN_DIM + sslot * 8;
        dOff[i] = rb * 64;
    }

    #pragma unroll
    for (int i = 0; i < 4; ++i) {
        __builtin_amdgcn_global_load_lds((const __attribute__((address_space(1))) void*)(aS[i]), (__attribute__((address_space(3))) void*)&Ah[0][dOff[i]], 16, 0, 0);
        __builtin_amdgcn_global_load_lds((const __attribute__((address_space(1))) void*)(bS[i]), (__attribute__((address_space(3))) void*)&Bh[0][dOff[i]], 16, 0, 0);
    }
    __syncthreads();

    int cur = 0;
    #pragma unroll 1
    for (int t = 0; t < 16; ++t) {
        if (t < 15) {
            const int kt = (t + 1) * 64;
            #pragma unroll
            for (int i = 0; i < 4; ++i) {
                __builtin_amdgcn_global_load_lds((const __attribute__((address_space(1))) void*)(aS[i] + kt), (__attribute__((address_space(3))) void*)&Ah[cur ^ 1][dOff[i]], 16, 0, 0);
                __builtin_amdgcn_global_load_lds((const __attribute__((address_space(1))) void*)(bS[i] + kt), (__attribute__((address_space(3))) void*)&Bh[cur ^ 1][dOff[i]], 16, 0, 0);
            }
        }
        #pragma unroll
        for (int h = 0; h < 2; ++h) {
            half8 bf[4];
            #pragma unroll
            for (int j = 0; j < 4; ++j) {
                const int rbv = wn * 64 + j * 16 + lr;
                const int sb = (h * 4 + lk) ^ (rbv & 7);
                bf[j] = *(const half8*)&Bh[cur][rbv * 64 + (sb << 3)];
            }
            #pragma unroll
            for (int hf = 0; hf < 2; ++hf) {
                half8 af[4];
                #pragma unroll
                for (int i = 0; i < 4; ++i) {
                    const int ra = wm * 128 + (hf * 4 + i) * 16 + lr;
                    const int sa = (h * 4 + lk) ^ (ra & 7);
                    af[i] = *(const half8*)&Ah[cur][ra * 64 + (sa << 3)];
                }
                #pragma unroll
                for (int i = 0; i < 4; ++i)
                    #pragma unroll
                    for (int j = 0; j < 4; ++j)
                        acc[hf * 4 + i][j] = __builtin_amdgcn_mfma_f32_16x16x32_f16(
                            af[i], bf[j], acc[hf * 4 + i][j], 0, 0, 0);
            }
        }
        __syncthreads();
        cur ^= 1;
    }
    #pragma unroll
    for (int i = 0; i < 8; ++i)
        #pragma unroll
        for (int j = 0; j < 4; ++j)
            #pragma unroll
            for (int q = 0; q < 4; ++q) {
                const int row = bm * 256 + wm * 128 + i * 16 + lk * 4 + q;
                const int col = bn * 256 + wn * 64 + j * 16 + lr;
                _Float16* fo = (_Float16*)((char*)out + (size_t)row * OUT_DIM * 4);
                fo[col] = (_Float16)acc[i][j][q];
            }
}

// ---------------------------------------------------------------- kernel C
// FUSED select (sel1+sel2+sel3): per row -- f16 fast row to registers,
// 2-level 256-bin histogram -> boundary sub-bucket; window +- DELTA_W;
// classify (ballot-reduced hi count, atomic slots); CSR replica chains
// inline (EXACT r13 order: single acc, ascending k, __fmaf_rn; fma w/ 0 is
// a bitwise no-op => nonzero-only chain identical); parallel tie-inclusive
// rank; encode from live registers; L2 norm; f32 write (after all f16
// reads => safe in-place).
__global__ __launch_bounds__(256)
void k_self(float* __restrict__ po, const float* __restrict__ x,
            const float* __restrict__ wvals, const unsigned short* __restrict__ widx,
            const int* __restrict__ wn, const float* __restrict__ wfull,
            int use_csr, const int* __restrict__ flag) {
    __shared__ unsigned int bins[256];
    __shared__ float fred[4];
    __shared__ unsigned int wsum[4];
    __shared__ int ired[4];
    __shared__ int s_b, s_b2;
    __shared__ unsigned int s_slot, s_hi1;
    __shared__ int bcol[64];
    __shared__ float bnp[64];
    __shared__ unsigned char bsel[64];
    __shared__ float xs[IN_DIM];

    const int row = blockIdx.x;
    const int tid = threadIdx.x;
    const int lane = tid & 63, wq = tid >> 6;
    const _Float16* fr = (const _Float16*)((const char*)po + (size_t)row * OUT_DIM * 4);

    half8 h0 = *(const half8*)&fr[tid * 8];
    half8 h1 = *(const half8*)&fr[2048 + tid * 8];
    float fv[16];
    float vmax = -1e30f;
    #pragma unroll
    for (int e = 0; e < 8; ++e) {
        fv[e] = (float)h0[e];
        fv[8 + e] = (float)h1[e];
        vmax = fmaxf(vmax, fmaxf(fv[e], fv[8 + e]));
    }
    #pragma unroll
    for (int off = 32; off > 0; off >>= 1)
        vmax = fmaxf(vmax, __shfl_xor(vmax, off));
    if (lane == 0) fred[wq] = vmax;
    bins[tid] = 0;
    if (tid == 0) { s_slot = 0; s_b = 0; s_b2 = 0; s_hi1 = 0; }
    __syncthreads();
    vmax = fmaxf(fmaxf(fmaxf(fred[0], fred[1]), fmaxf(fred[2], fred[3])), 1e-6f);
    const float scale1 = 256.0f / vmax;
    const float invscale1 = vmax * (1.0f / 256.0f);

    // pass 1
    #pragma unroll
    for (int e = 0; e < 16; ++e) {
        float f = fv[e];
        if (f > 0.0f) {
            int b = (int)(f * scale1);
            if (b > 255) b = 255;
            atomicAdd(&bins[b], 1u);
        }
    }
    __syncthreads();
    {
        const unsigned int c = bins[255 - tid];
        unsigned int sc = c;
        #pragma unroll
        for (int off = 1; off < 64; off <<= 1) {
            unsigned int t2 = __shfl_up(sc, off);
            if (lane >= off) sc += t2;
        }
        if (lane == 63) wsum[wq] = sc;
        __syncthreads();
        for (int q = 0; q < wq; ++q) sc += wsum[q];
        if ((int)sc >= K_TOP && (int)(sc - c) < K_TOP) {
            s_b = 255 - tid;
            s_hi1 = sc - c;
        }
    }
    __syncthreads();
    const int b1 = s_b;
    const unsigned int hi1 = s_hi1;
    const float blo = (float)b1 * invscale1;
    const float scale2 = scale1 * 256.0f;
    const float s2w = invscale1 * (1.0f / 256.0f);

    bins[tid] = 0;
    __syncthreads();
    #pragma unroll
    for (int e = 0; e < 16; ++e) {
        float f = fv[e];
        if (f > 0.0f) {
            int b = (int)(f * scale1);
            if (b > 255) b = 255;
            if (b == b1) {
                int b2 = (int)((f - blo) * scale2);
                if (b2 < 0) b2 = 0;
                if (b2 > 255) b2 = 255;
                atomicAdd(&bins[b2], 1u);
            }
        }
    }
    __syncthreads();
    {
        const unsigned int c = bins[255 - tid];
        unsigned int sc = c;
        #pragma unroll
        for (int off = 1; off < 64; off <<= 1) {
            unsigned int t2 = __shfl_up(sc, off);
            if (lane >= off) sc += t2;
        }
        if (lane == 63) wsum[wq] = sc;
        __syncthreads();
        for (int q = 0; q < wq; ++q) sc += wsum[q];
        if ((int)(hi1 + sc) >= K_TOP && (int)(hi1 + sc - c) < K_TOP)
            s_b2 = 255 - tid;
    }
    __syncthreads();
    const float thi = blo + (float)(s_b2 + 1) * s2w + DELTA_W;
    const float tlo = blo + (float)s_b2 * s2w - DELTA_W;

    // classify: per-thread hi count (reduced), atomic window slots
    int hic = 0;
    #pragma unroll
    for (int e = 0; e < 16; ++e) {
        float f = fv[e];
        if (f > thi) ++hic;
        else if (f >= tlo) {
            unsigned int p = atomicAdd(&s_slot, 1u);
            const int j = (e < 8) ? (tid * 8 + e) : (2048 + tid * 8 + e - 8);
            if (p < 64) bcol[p] = j;
        }
    }
    #pragma unroll
    for (int off = 32; off > 0; off >>= 1)
        hic += __shfl_xor(hic, off);
    if (lane == 0) ired[wq] = hic;
    __syncthreads();
    const int hi = ired[0] + ired[1] + ired[2] + ired[3];
    const int nb = (int)s_slot;
    const int nbc = nb > 64 ? 64 : nb;
    int krem = K_TOP - hi; if (krem > nb) krem = nb; if (krem < 0) krem = 0;
    const bool need = (nb != krem);          // uniform (all from shared/reduced)

    if (need) {
        const bool bipolar = (*flag == 0);
        float4 xv = ((const float4*)(x + (size_t)row * IN_DIM))[tid];
        if (bipolar) {
            xv.x = __fmul_rn(__fadd_rn(xv.x, -0.5f), 2.0f);
            xv.y = __fmul_rn(__fadd_rn(xv.y, -0.5f), 2.0f);
            xv.z = __fmul_rn(__fadd_rn(xv.z, -0.5f), 2.0f);
            xv.w = __fmul_rn(__fadd_rn(xv.w, -0.5f), 2.0f);
        }
        ((float4*)xs)[tid] = xv;
        __syncthreads();                     // xs visible
        if (tid < nbc) {
            const int col = bcol[tid];
            float p = 0.0f;
            if (use_csr) {
                const int n4 = (wn[col] + 3) >> 2;
                const float4* v4 = (const float4*)(wvals + (size_t)col * 256);
                const ushort4* i4 = (const ushort4*)(widx + (size_t)col * 256);
                #pragma unroll 2
                for (int i = 0; i < n4; ++i) {
                    float4 vv = v4[i];
                    ushort4 ii = i4[i];
                    p = __fmaf_rn(xs[ii.x], vv.x, p);
                    p = __fmaf_rn(xs[ii.y], vv.y, p);
                    p = __fmaf_rn(xs[ii.z], vv.z, p);
                    p = __fmaf_rn(xs[ii.w], vv.w, p);
                }
            } else {
                const float4* wr4 = (const float4*)(wfull + (size_t)col * IN_DIM);
                const float4* xs4 = (const float4*)xs;
                #pragma unroll 4
                for (int i = 0; i < IN_DIM / 4; ++i) {
                    float4 xq = xs4[i];
                    float4 wq2 = wr4[i];
                    p = __fmaf_rn(xq.x, wq2.x, p);
                    p = __fmaf_rn(xq.y, wq2.y, p);
                    p = __fmaf_rn(xq.z, wq2.z, p);
                    p = __fmaf_rn(xq.w, wq2.w, p);
                }
            }
            bnp[tid] = p;
        }
        __syncthreads();                     // bnp visible
        if (tid < nbc) {
            const float v = bnp[tid];
            int gc = 0;
            for (int l = 0; l < nbc; ++l) gc += (bnp[l] > v);
            bsel[tid] = (gc < krem) ? 1 : 0;
        }
        __syncthreads();                     // bsel visible
    }

    // encode from live registers, norm, write f32
    float ov[16];
    float nrm2 = 0.0f;
    #pragma unroll
    for (int e = 0; e < 16; ++e) {
        float f = fv[e];
        const int j = (e < 8) ? (tid * 8 + e) : (2048 + tid * 8 + e - 8);
        bool sel = (f > thi);
        float val = f;
        if (!sel && f >= tlo) {
            if (!need) sel = true;
            else {
                for (int m = 0; m < nbc; ++m)
                    if (bcol[m] == j) {
                        sel = (bsel[m] != 0);
                        val = bnp[m];
                        break;
                    }
            }
        }
        float eo = (sel && val > 0.0f) ? val : 0.0f;
        ov[e] = eo;
        nrm2 += eo * eo;
    }
    #pragma unroll
    for (int off = 32; off > 0; off >>= 1)
        nrm2 += __shfl_xor(nrm2, off);
    if (lane == 0) fred[wq] = nrm2;
    __syncthreads();
    const float total = fred[0] + fred[1] + fred[2] + fred[3];
    const float inv = 1.0f / fmaxf(sqrtf(total), 1e-12f);

    float4* p4 = (float4*)(po + (size_t)row * OUT_DIM);
    #pragma unroll
    for (int h = 0; h < 2; ++h) {
        const int base = (h == 0) ? 0 : 8;
        const int fi = (h == 0) ? (tid * 2) : (512 + tid * 2);
        float4 o0 = make_float4(ov[base + 0] * inv, ov[base + 1] * inv,
                                ov[base + 2] * inv, ov[base + 3] * inv);
        float4 o1 = make_float4(ov[base + 4] * inv, ov[base + 5] * inv,
                                ov[base + 6] * inv, ov[base + 7] * inv);
        p4[fi] = o0;
        p4[fi + 1] = o1;
    }
}

// ---------------------------------------------------------------- launch
extern "C" void kernel_launch(void* const* d_in, const int* in_sizes, int n_in,
                              void* d_out, int out_size, void* d_ws, size_t ws_size,
                              hipStream_t stream) {
    const float* x = (const float*)d_in[0];
    const float* w = (const float*)d_in[1];
    float* out = (float*)d_out;
    int* flag = (int*)d_ws;
    const int use_csr = (ws_size >= WS_NEED3) ? 1 : 0;

    hipMemsetAsync(flag, 0, sizeof(int), stream);
    k_hasneg<<<2048, 256, 0, stream>>>(x, BATCH * IN_DIM, flag);

    _Float16* xh = (_Float16*)((char*)d_ws + WS_XH_OFF);
    _Float16* wh = (_Float16*)((char*)d_ws + WS_WH_OFF);
    float* wv = (float*)((char*)d_ws + WS_WV_OFF);
    unsigned short* wi = (unsigned short*)((char*)d_ws + WS_WI_OFF);
    int* wn = (int*)((char*)d_ws + WS_WN_OFF);

    k_cvt2<<<OUT_DIM / 4, 256, 0, stream>>>(x, w, xh, wh, wv, wi, wn,
                                            use_csr, flag);
    dim3 g(BATCH / 256, OUT_DIM / 256);
    k_gemm16<<<g, 512, 0, stream>>>(xh, wh, out);

    k_self<<<BATCH, 256, 0, stream>>>(out, x, wv, wi, wn, w, use_csr, flag);
}